// Round 2
// baseline (1342.958 us; speedup 1.0000x reference)
//
#include <hip/hip_runtime.h>
#include <cstddef>

#define HD 128   // hidden dim
#define NREL 65
#define BM 64
#define BN 64
#define BK 16

__device__ __forceinline__ float reluf(float v) { return v > 0.f ? v : 0.f; }

// ---------------- transpose 128x128 (loopW -> loopW^T) ----------------
__global__ void transpose128(const float* __restrict__ in, float* __restrict__ out) {
  out[(size_t)blockIdx.x * HD + threadIdx.x] = in[(size_t)threadIdx.x * HD + blockIdx.x];
}

// ---------------- edge bucketing by relation (counting sort, 64-aligned buckets) ----------------
__global__ void edge_hist(const int* __restrict__ et, int* __restrict__ counts, int E) {
  int i = blockIdx.x * blockDim.x + threadIdx.x;
  if (i < E) atomicAdd(&counts[et[i]], 1);
}

__global__ void rel_offsets(const int* __restrict__ counts, int* __restrict__ offs) {
  if (threadIdx.x == 0 && blockIdx.x == 0) {
    int o = 0;
    for (int r = 0; r < NREL; ++r) { offs[r] = o; o += (counts[r] + 63) & ~63; }
    offs[NREL] = o;
  }
}

__global__ void edge_scatter(const int* __restrict__ src, const int* __restrict__ dst,
                             const int* __restrict__ et, const int* __restrict__ offs,
                             int* __restrict__ cursor, int* __restrict__ ssrc,
                             int* __restrict__ sdst, int* __restrict__ chunk_rel, int E) {
  int i = blockIdx.x * blockDim.x + threadIdx.x;
  if (i >= E) return;
  int r = et[i];
  int slot = offs[r] + atomicAdd(&cursor[r], 1);
  ssrc[slot] = src[i];
  sdst[slot] = dst[i];
  chunk_rel[slot >> 6] = r;   // all writers of a chunk write the same r (64-aligned buckets)
}

// ---------------- edge message GEMM: one block per 64-edge chunk (single relation) ----------------
// msg[64,128] = Xg[64,128] @ W[r][128,128]; scatter-add rows into agg[dst].
__global__ __launch_bounds__(256) void edge_gemm(
    const float* __restrict__ x, const float* __restrict__ W,
    const int* __restrict__ ssrc, const int* __restrict__ sdst,
    const int* __restrict__ chunk_rel, float* __restrict__ agg) {
  int chunk = blockIdx.x;
  int rel = chunk_rel[chunk];
  if (rel < 0) return;                       // empty / all-pad chunk

  __shared__ __align__(16) float As[32][64];     // [k][edge]
  __shared__ __align__(16) float Bs[32][128];    // [k][out]
  __shared__ int dsts[64];

  int tid = threadIdx.x;
  int base = chunk * 64;
  if (tid < 64) dsts[tid] = sdst[base + tid];

  int arow = tid >> 2;                 // 0..63 edge slot this thread gathers
  int akoff = (tid & 3) * 8;           // k sub-offset 0,8,16,24
  int srow = ssrc[base + arow];        // -1 for pad slots
  const float* xr = (srow >= 0) ? x + (size_t)srow * HD : nullptr;

  int bk = tid >> 3;                   // 0..31
  int bn = (tid & 7) * 16;             // 0..112
  const float* Wb = W + (size_t)rel * HD * HD;

  int trow = tid >> 4;                 // 0..15 (4 rows each)
  int tcol = tid & 15;                 // 0..15 (8 cols each)
  float acc[4][8] = {};

  for (int k0 = 0; k0 < HD; k0 += 32) {
    // stage A (gathered x rows; pads -> 0)
    float4 va = make_float4(0.f, 0.f, 0.f, 0.f), vb = va;
    if (xr) {
      va = *(const float4*)(xr + k0 + akoff);
      vb = *(const float4*)(xr + k0 + akoff + 4);
    }
    As[akoff + 0][arow] = va.x; As[akoff + 1][arow] = va.y;
    As[akoff + 2][arow] = va.z; As[akoff + 3][arow] = va.w;
    As[akoff + 4][arow] = vb.x; As[akoff + 5][arow] = vb.y;
    As[akoff + 6][arow] = vb.z; As[akoff + 7][arow] = vb.w;
    // stage B (W[r] slice, read once per chunk)
    const float* wr = Wb + (size_t)(k0 + bk) * HD + bn;
    *(float4*)&Bs[bk][bn + 0]  = *(const float4*)(wr + 0);
    *(float4*)&Bs[bk][bn + 4]  = *(const float4*)(wr + 4);
    *(float4*)&Bs[bk][bn + 8]  = *(const float4*)(wr + 8);
    *(float4*)&Bs[bk][bn + 12] = *(const float4*)(wr + 12);
    __syncthreads();
#pragma unroll
    for (int kk = 0; kk < 32; ++kk) {
      float4 a4 = *(const float4*)&As[kk][trow * 4];
      float4 b0 = *(const float4*)&Bs[kk][tcol * 8];
      float4 b1 = *(const float4*)&Bs[kk][tcol * 8 + 4];
      float a[4] = {a4.x, a4.y, a4.z, a4.w};
      float b[8] = {b0.x, b0.y, b0.z, b0.w, b1.x, b1.y, b1.z, b1.w};
#pragma unroll
      for (int i = 0; i < 4; ++i)
#pragma unroll
        for (int j = 0; j < 8; ++j) acc[i][j] += a[i] * b[j];
    }
    __syncthreads();
  }

#pragma unroll
  for (int i = 0; i < 4; ++i) {
    int d = dsts[trow * 4 + i];
    if (d >= 0) {
      float* ap = agg + (size_t)d * HD + tcol * 8;
#pragma unroll
      for (int j = 0; j < 8; ++j) atomicAdd(ap + j, acc[i][j]);
    }
  }
}

// ---------------- generic NT GEMM: C[m,n] = epi( sum_k A[m,k]*B[n,k] ) ----------------
template<bool DUAL, int EPI>
__global__ __launch_bounds__(256) void gemm_nt(
    const float* __restrict__ A, const float* __restrict__ B1t, const float* __restrict__ B2t,
    const float* __restrict__ bias1, const float* __restrict__ bias2,
    const float* __restrict__ addend, float* __restrict__ C, float* __restrict__ colsum,
    int M, int N, int K) {
  __shared__ __align__(16) float As[BK][BM];
  __shared__ __align__(16) float B1s[BK][BN];
  __shared__ __align__(16) float B2s[BK][BN];
  __shared__ float cs[2][BN];

  int tid = threadIdx.x;
  int trow = tid >> 4;
  int tcol = tid & 15;
  int row0 = blockIdx.y * BM;
  int col0 = blockIdx.x * BN;
  int lr = tid >> 2;
  int lk = (tid & 3) * 4;

  float acc1[4][4] = {};
  float acc2[4][4] = {};

  for (int k0 = 0; k0 < K; k0 += BK) {
    {
      int gr = row0 + lr;
      float4 v = make_float4(0.f, 0.f, 0.f, 0.f);
      if (gr < M) v = *(const float4*)&A[(size_t)gr * K + k0 + lk];
      As[lk + 0][lr] = v.x; As[lk + 1][lr] = v.y; As[lk + 2][lr] = v.z; As[lk + 3][lr] = v.w;
    }
    {
      int gn = col0 + lr;
      float4 v = *(const float4*)&B1t[(size_t)gn * K + k0 + lk];
      B1s[lk + 0][lr] = v.x; B1s[lk + 1][lr] = v.y; B1s[lk + 2][lr] = v.z; B1s[lk + 3][lr] = v.w;
      if constexpr (DUAL) {
        float4 w = *(const float4*)&B2t[(size_t)gn * K + k0 + lk];
        B2s[lk + 0][lr] = w.x; B2s[lk + 1][lr] = w.y; B2s[lk + 2][lr] = w.z; B2s[lk + 3][lr] = w.w;
      }
    }
    __syncthreads();
#pragma unroll
    for (int kk = 0; kk < BK; ++kk) {
      float4 a4 = *(const float4*)&As[kk][trow * 4];
      float4 b4 = *(const float4*)&B1s[kk][tcol * 4];
      float a[4] = {a4.x, a4.y, a4.z, a4.w};
      float b[4] = {b4.x, b4.y, b4.z, b4.w};
#pragma unroll
      for (int i = 0; i < 4; ++i)
#pragma unroll
        for (int j = 0; j < 4; ++j) acc1[i][j] += a[i] * b[j];
      if constexpr (DUAL) {
        float4 c4 = *(const float4*)&B2s[kk][tcol * 4];
        float c[4] = {c4.x, c4.y, c4.z, c4.w};
#pragma unroll
        for (int i = 0; i < 4; ++i)
#pragma unroll
          for (int j = 0; j < 4; ++j) acc2[i][j] += a[i] * c[j];
      }
    }
    __syncthreads();
  }

  int ccol = col0 + tcol * 4;
  if constexpr (EPI == 2) {
    float s[4] = {0, 0, 0, 0}, sq[4] = {0, 0, 0, 0};
#pragma unroll
    for (int i = 0; i < 4; ++i) {
      int row = row0 + trow * 4 + i;
      if (row < M) {
#pragma unroll
        for (int j = 0; j < 4; ++j) {
          int col = ccol + j;
          float v = reluf(acc1[i][j] + bias1[col] + addend[(size_t)row * N + col])
                  + reluf(acc2[i][j] + bias2[col]);
          C[(size_t)row * N + col] = v;
          s[j] += v; sq[j] += v * v;
        }
      }
    }
    __syncthreads();
    if (tid < 2 * BN) ((float*)cs)[tid] = 0.f;
    __syncthreads();
#pragma unroll
    for (int j = 0; j < 4; ++j) {
      atomicAdd(&cs[0][tcol * 4 + j], s[j]);
      atomicAdd(&cs[1][tcol * 4 + j], sq[j]);
    }
    __syncthreads();
    if (tid < BN) {
      atomicAdd(&colsum[col0 + tid], cs[0][tid]);
      atomicAdd(&colsum[N + col0 + tid], cs[1][tid]);
    }
  } else {
#pragma unroll
    for (int i = 0; i < 4; ++i) {
      int row = row0 + trow * 4 + i;
      if (row < M) {
#pragma unroll
        for (int j = 0; j < 4; ++j) {
          int col = ccol + j;
          float v = acc1[i][j] + bias1[col];
          if constexpr (EPI == 1) v = reluf(v);
          C[(size_t)row * N + col] = v;
        }
      }
    }
  }
}

// ---------------- BatchNorm apply ----------------
__global__ void bn_apply(float* __restrict__ h, const float* __restrict__ colsum,
                         const float* __restrict__ gamma, const float* __restrict__ beta, int M) {
  size_t idx = (size_t)blockIdx.x * blockDim.x + threadIdx.x;
  if (idx >= (size_t)M * HD) return;
  int c = (int)(idx & (HD - 1));
  float invM = 1.f / (float)M;
  float mu = colsum[c] * invM;
  float var = colsum[HD + c] * invM - mu * mu;
  float inv = rsqrtf(var + 1e-5f);
  h[idx] = (h[idx] - mu) * inv * gamma[c] + beta[c];
}

// ---------------- segment-sum accumulation ----------------
__global__ void seg_accum(const float* __restrict__ h, const int* __restrict__ gid,
                          const int* __restrict__ mid, float* __restrict__ gsum,
                          float* __restrict__ gcnt, float* __restrict__ msum,
                          float* __restrict__ mcnt, int Nn) {
  int node = blockIdx.x * 2 + (threadIdx.x >> 7);
  if (node >= Nn) return;
  int c = threadIdx.x & 127;
  float v = h[(size_t)node * HD + c];
  int g = gid[node], m = mid[node];
  atomicAdd(&gsum[(size_t)g * HD + c], v);
  atomicAdd(&msum[(size_t)m * HD + c], v);
  if (c == 0) { atomicAdd(&gcnt[g], 1.f); atomicAdd(&mcnt[m], 1.f); }
}

__global__ void seg_norm(const float* __restrict__ sum, const float* __restrict__ cnt,
                         float* __restrict__ out, int R) {
  size_t idx = (size_t)blockIdx.x * blockDim.x + threadIdx.x;
  if (idx >= (size_t)R * HD) return;
  int r = (int)(idx >> 7);
  out[idx] = sum[idx] / fmaxf(cnt[r], 1.f);
}

extern "C" void kernel_launch(void* const* d_in, const int* in_sizes, int n_in,
                              void* d_out, int out_size, void* d_ws, size_t ws_size,
                              hipStream_t stream) {
  const float* x0     = (const float*)d_in[0];
  const int*   src    = (const int*)d_in[1];
  const int*   dst    = (const int*)d_in[2];
  const int*   etype  = (const int*)d_in[3];
  const int*   gids   = (const int*)d_in[4];
  const int*   mids   = (const int*)d_in[5];
  const float* W1     = (const float*)d_in[6];
  const float* loopW1 = (const float*)d_in[7];
  const float* b1     = (const float*)d_in[8];
  const float* resW1  = (const float*)d_in[9];
  const float* resb1  = (const float*)d_in[10];
  const float* g1     = (const float*)d_in[11];
  const float* be1    = (const float*)d_in[12];
  const float* W2     = (const float*)d_in[13];
  const float* loopW2 = (const float*)d_in[14];
  const float* b2     = (const float*)d_in[15];
  const float* resW2  = (const float*)d_in[16];
  const float* resb2  = (const float*)d_in[17];
  const float* g2     = (const float*)d_in[18];
  const float* be2    = (const float*)d_in[19];
  const float* featW  = (const float*)d_in[20];   // [512,128]
  const float* featb  = (const float*)d_in[21];
  const float* mW1    = (const float*)d_in[22];   // [512,512]
  const float* mb1    = (const float*)d_in[23];
  const float* mW2    = (const float*)d_in[24];   // [256,512]
  const float* mb2    = (const float*)d_in[25];

  const int N = in_sizes[0] / HD;   // 30000
  const int E = in_sizes[1];        // 90000
  const int NG = 1500, NM = 6001, FFN = 512, OUT2 = 256;
  const int NCH = (E + 63) / 64 + NREL;   // upper bound on padded chunk count

  float* ws = (float*)d_ws;
  size_t off = 0;
  auto alloc = [&](size_t n) { float* p = ws + off; off += (n + 63) & ~((size_t)63); return p; };
  float* agg    = alloc((size_t)N * HD);
  float* h1     = alloc((size_t)N * HD);
  float* h2     = alloc((size_t)N * HD);
  float* lwT1   = alloc(HD * HD);
  float* lwT2   = alloc(HD * HD);
  float* colsum = alloc(2 * HD);
  float* gsum   = alloc((size_t)NG * HD);
  float* gcnt   = alloc(NG);
  float* msum   = alloc((size_t)NM * HD);
  float* mcnt   = alloc(NM);
  int* counts    = (int*)alloc(NREL);
  int* offs      = (int*)alloc(NREL + 1);
  int* cursor    = (int*)alloc(NREL);
  int* chunk_rel = (int*)alloc(NCH);
  int* ssrc      = (int*)alloc((size_t)NCH * 64);
  int* sdst      = (int*)alloc((size_t)NCH * 64);
  float* fbuf = h1;   // dead after layer-2 GEMM -> head intermediate f
  float* obuf = agg;  // dead after layer-2 GEMM -> head intermediate o

  float* out_gf = (float*)d_out;
  float* out_gl = out_gf + (size_t)NG * HD;
  float* out_sb = out_gl + (size_t)NG * OUT2;

  dim3 blk(256);
  dim3 gridDual(HD / BN, (N + BM - 1) / BM);
  int bnBlocks = (int)(((size_t)N * HD + 255) / 256);

  transpose128<<<HD, HD, 0, stream>>>(loopW1, lwT1);
  transpose128<<<HD, HD, 0, stream>>>(loopW2, lwT2);

  // ---- bucket edges by relation (once; reused by both layers) ----
  hipMemsetAsync(counts, 0, NREL * sizeof(int), stream);
  hipMemsetAsync(cursor, 0, NREL * sizeof(int), stream);
  hipMemsetAsync(chunk_rel, 0xFF, NCH * sizeof(int), stream);
  hipMemsetAsync(ssrc, 0xFF, (size_t)NCH * 64 * sizeof(int), stream);
  hipMemsetAsync(sdst, 0xFF, (size_t)NCH * 64 * sizeof(int), stream);
  edge_hist<<<(E + 255) / 256, blk, 0, stream>>>(etype, counts, E);
  rel_offsets<<<1, 64, 0, stream>>>(counts, offs);
  edge_scatter<<<(E + 255) / 256, blk, 0, stream>>>(src, dst, etype, offs, cursor,
                                                    ssrc, sdst, chunk_rel, E);

  // ---------------- layer 1 ----------------
  hipMemsetAsync(agg, 0, (size_t)N * HD * sizeof(float), stream);
  hipMemsetAsync(colsum, 0, 2 * HD * sizeof(float), stream);
  edge_gemm<<<NCH, blk, 0, stream>>>(x0, W1, ssrc, sdst, chunk_rel, agg);
  gemm_nt<true, 2><<<gridDual, blk, 0, stream>>>(x0, lwT1, resW1, b1, resb1, agg, h1, colsum, N, HD, HD);
  bn_apply<<<bnBlocks, blk, 0, stream>>>(h1, colsum, g1, be1, N);

  // ---------------- layer 2 ----------------
  hipMemsetAsync(agg, 0, (size_t)N * HD * sizeof(float), stream);
  hipMemsetAsync(colsum, 0, 2 * HD * sizeof(float), stream);
  edge_gemm<<<NCH, blk, 0, stream>>>(h1, W2, ssrc, sdst, chunk_rel, agg);
  gemm_nt<true, 2><<<gridDual, blk, 0, stream>>>(h1, lwT2, resW2, b2, resb2, agg, h2, colsum, N, HD, HD);
  bn_apply<<<bnBlocks, blk, 0, stream>>>(h2, colsum, g2, be2, N);

  // ---------------- readout ----------------
  hipMemsetAsync(gsum, 0, (size_t)NG * HD * sizeof(float), stream);
  hipMemsetAsync(gcnt, 0, NG * sizeof(float), stream);
  hipMemsetAsync(msum, 0, (size_t)NM * HD * sizeof(float), stream);
  hipMemsetAsync(mcnt, 0, NM * sizeof(float), stream);
  seg_accum<<<(N + 1) / 2, blk, 0, stream>>>(h2, gids, mids, gsum, gcnt, msum, mcnt, N);
  seg_norm<<<(int)(((size_t)NG * HD + 255) / 256), blk, 0, stream>>>(gsum, gcnt, out_gf, NG);
  seg_norm<<<(int)(((size_t)NM * HD + 255) / 256), blk, 0, stream>>>(msum, mcnt, msum, NM);

  auto run_head = [&](const float* in, int M, float* outp) {
    dim3 gA(FFN / BN, (M + BM - 1) / BM);
    gemm_nt<false, 0><<<gA, blk, 0, stream>>>(in, featW, nullptr, featb, nullptr, nullptr, fbuf, nullptr, M, FFN, HD);
    dim3 gB(FFN / BN, (M + BM - 1) / BM);
    gemm_nt<false, 1><<<gB, blk, 0, stream>>>(fbuf, mW1, nullptr, mb1, nullptr, nullptr, obuf, nullptr, M, FFN, FFN);
    dim3 gC(OUT2 / BN, (M + BM - 1) / BM);
    gemm_nt<false, 0><<<gC, blk, 0, stream>>>(obuf, mW2, nullptr, mb2, nullptr, nullptr, outp, nullptr, M, OUT2, FFN);
  };
  run_head(out_gf, NG, out_gl);
  run_head(msum + HD, NM - 1, out_sb);
}

// Round 3
// 760.508 us; speedup vs baseline: 1.7659x; 1.7659x over previous
//
#include <hip/hip_runtime.h>
#include <cstddef>

#define HD 128   // hidden dim
#define NREL 65
#define BM 64
#define BN 64
#define BK 16

__device__ __forceinline__ float reluf(float v) { return v > 0.f ? v : 0.f; }

// ---------------- transpose 128x128 (loopW -> loopW^T) ----------------
__global__ void transpose128(const float* __restrict__ in, float* __restrict__ out) {
  out[(size_t)blockIdx.x * HD + threadIdx.x] = in[(size_t)threadIdx.x * HD + blockIdx.x];
}

// ---------------- edge bucketing by relation (counting sort, 64-aligned buckets) ----------------
__global__ void edge_hist(const int* __restrict__ et, int* __restrict__ counts, int E) {
  int i = blockIdx.x * blockDim.x + threadIdx.x;
  if (i < E) atomicAdd(&counts[et[i]], 1);
}

__global__ void rel_offsets(const int* __restrict__ counts, int* __restrict__ offs) {
  if (threadIdx.x == 0 && blockIdx.x == 0) {
    int o = 0;
    for (int r = 0; r < NREL; ++r) { offs[r] = o; o += (counts[r] + 63) & ~63; }
    offs[NREL] = o;
  }
}

__global__ void edge_scatter(const int* __restrict__ src, const int* __restrict__ dst,
                             const int* __restrict__ et, const int* __restrict__ offs,
                             int* __restrict__ cursor, int* __restrict__ ssrc,
                             int* __restrict__ sdst, int* __restrict__ chunk_rel, int E) {
  int i = blockIdx.x * blockDim.x + threadIdx.x;
  if (i >= E) return;
  int r = et[i];
  int slot = offs[r] + atomicAdd(&cursor[r], 1);
  ssrc[slot] = src[i];
  sdst[slot] = dst[i];
  chunk_rel[slot >> 6] = r;   // 64-aligned buckets: all writers of a chunk agree
}

// ---------------- edge message GEMM: one block per 64-edge chunk (single relation) ----------------
// msg[64,128] = Xg[64,128] @ W[r][128,128]; coalesced atomic scatter-add rows into agg[dst].
__global__ __launch_bounds__(256) void edge_gemm(
    const float* __restrict__ x, const float* __restrict__ W,
    const int* __restrict__ ssrc, const int* __restrict__ sdst,
    const int* __restrict__ chunk_rel, float* __restrict__ agg) {
  int chunk = blockIdx.x;
  int rel = chunk_rel[chunk];
  if (rel < 0) return;                       // empty / all-pad chunk

  __shared__ __align__(16) float As[32][68];     // [k][edge], pad->writes <=2-way, 16B rows
  __shared__ __align__(16) float Bs[32][132];    // [k][out], linear-staged, 16B rows
  __shared__ int dsts[64];

  int tid = threadIdx.x;
  int base = chunk * 64;
  if (tid < 64) dsts[tid] = sdst[base + tid];

  // A staging: edge-per-lane, k-group per 64-thread wave
  int edge = tid & 63;
  int wk = tid >> 6;                    // 0..3 -> k sub-range wk*8..wk*8+7
  int srow = ssrc[base + edge];         // -1 for pad slots (dst guard drops them)
  const float* xr = x + (size_t)(srow >= 0 ? srow : 0) * HD;

  const float* Wb = W + (size_t)rel * HD * HD;

  int trow = tid >> 4;                  // 0..15 (4 rows each)
  int tcol = tid & 15;                  // 0..15 (cols tcol*4.. and 64+tcol*4..)
  float acc[4][8] = {};

  for (int k0 = 0; k0 < HD; k0 += 32) {
    // stage A (gathered x rows; transpose to [k][edge])
    {
      float4 va = *(const float4*)(xr + k0 + wk * 8);
      float4 vb = *(const float4*)(xr + k0 + wk * 8 + 4);
      int kb = wk * 8;
      As[kb + 0][edge] = va.x; As[kb + 1][edge] = va.y;
      As[kb + 2][edge] = va.z; As[kb + 3][edge] = va.w;
      As[kb + 4][edge] = vb.x; As[kb + 5][edge] = vb.y;
      As[kb + 6][edge] = vb.z; As[kb + 7][edge] = vb.w;
    }
    // stage B linearly: lane i -> flat 16B chunk i (coalesced global, conflict-free LDS)
#pragma unroll
    for (int pass = 0; pass < 4; ++pass) {
      int idx = pass * 1024 + tid * 4;
      int kk2 = idx >> 7, nn = idx & 127;
      *(float4*)&Bs[kk2][nn] = *(const float4*)(Wb + (size_t)(k0 + kk2) * HD + nn);
    }
    __syncthreads();
#pragma unroll
    for (int kk = 0; kk < 32; ++kk) {
      float4 a4 = *(const float4*)&As[kk][trow * 4];
      float4 b0 = *(const float4*)&Bs[kk][tcol * 4];
      float4 b1 = *(const float4*)&Bs[kk][64 + tcol * 4];
      float a[4] = {a4.x, a4.y, a4.z, a4.w};
      float b[8] = {b0.x, b0.y, b0.z, b0.w, b1.x, b1.y, b1.z, b1.w};
#pragma unroll
      for (int i = 0; i < 4; ++i)
#pragma unroll
        for (int j = 0; j < 8; ++j) acc[i][j] += a[i] * b[j];
    }
    __syncthreads();
  }

  // epilogue: stage msg rows into Bs (two 32-row halves), wave-coalesced atomics
  for (int h = 0; h < 2; ++h) {
    __syncthreads();
    if ((trow >> 3) == h) {
      int rbase = trow * 4 - h * 32;
#pragma unroll
      for (int i = 0; i < 4; ++i) {
        *(float4*)&Bs[rbase + i][tcol * 4]      = *(float4*)&acc[i][0];
        *(float4*)&Bs[rbase + i][64 + tcol * 4] = *(float4*)&acc[i][4];
      }
    }
    __syncthreads();
#pragma unroll
    for (int it = 0; it < 16; ++it) {
      int row = it * 2 + (tid >> 7);        // 0..31
      int col = tid & 127;                  // wave = 64 consecutive cols of one row
      int d = dsts[h * 32 + row];
      if (d >= 0) atomicAdd(&agg[(size_t)d * HD + col], Bs[row][col]);
    }
  }
}

// ---------------- generic NT GEMM: C[m,n] = epi( sum_k A[m,k]*B[n,k] ) ----------------
template<bool DUAL, int EPI>
__global__ __launch_bounds__(256) void gemm_nt(
    const float* __restrict__ A, const float* __restrict__ B1t, const float* __restrict__ B2t,
    const float* __restrict__ bias1, const float* __restrict__ bias2,
    const float* __restrict__ addend, float* __restrict__ C, float* __restrict__ colsum,
    int M, int N, int K) {
  __shared__ __align__(16) float As[BK][BM];
  __shared__ __align__(16) float B1s[BK][BN];
  __shared__ __align__(16) float B2s[BK][BN];
  __shared__ float cs[2][BN];

  int tid = threadIdx.x;
  int trow = tid >> 4;
  int tcol = tid & 15;
  int row0 = blockIdx.y * BM;
  int col0 = blockIdx.x * BN;
  int lr = tid >> 2;
  int lk = (tid & 3) * 4;

  float acc1[4][4] = {};
  float acc2[4][4] = {};

  for (int k0 = 0; k0 < K; k0 += BK) {
    {
      int gr = row0 + lr;
      float4 v = make_float4(0.f, 0.f, 0.f, 0.f);
      if (gr < M) v = *(const float4*)&A[(size_t)gr * K + k0 + lk];
      As[lk + 0][lr] = v.x; As[lk + 1][lr] = v.y; As[lk + 2][lr] = v.z; As[lk + 3][lr] = v.w;
    }
    {
      int gn = col0 + lr;
      float4 v = *(const float4*)&B1t[(size_t)gn * K + k0 + lk];
      B1s[lk + 0][lr] = v.x; B1s[lk + 1][lr] = v.y; B1s[lk + 2][lr] = v.z; B1s[lk + 3][lr] = v.w;
      if constexpr (DUAL) {
        float4 w = *(const float4*)&B2t[(size_t)gn * K + k0 + lk];
        B2s[lk + 0][lr] = w.x; B2s[lk + 1][lr] = w.y; B2s[lk + 2][lr] = w.z; B2s[lk + 3][lr] = w.w;
      }
    }
    __syncthreads();
#pragma unroll
    for (int kk = 0; kk < BK; ++kk) {
      float4 a4 = *(const float4*)&As[kk][trow * 4];
      float4 b4 = *(const float4*)&B1s[kk][tcol * 4];
      float a[4] = {a4.x, a4.y, a4.z, a4.w};
      float b[4] = {b4.x, b4.y, b4.z, b4.w};
#pragma unroll
      for (int i = 0; i < 4; ++i)
#pragma unroll
        for (int j = 0; j < 4; ++j) acc1[i][j] += a[i] * b[j];
      if constexpr (DUAL) {
        float4 c4 = *(const float4*)&B2s[kk][tcol * 4];
        float c[4] = {c4.x, c4.y, c4.z, c4.w};
#pragma unroll
        for (int i = 0; i < 4; ++i)
#pragma unroll
          for (int j = 0; j < 4; ++j) acc2[i][j] += a[i] * c[j];
      }
    }
    __syncthreads();
  }

  int ccol = col0 + tcol * 4;
  if constexpr (EPI == 2) {
    float s[4] = {0, 0, 0, 0}, sq[4] = {0, 0, 0, 0};
#pragma unroll
    for (int i = 0; i < 4; ++i) {
      int row = row0 + trow * 4 + i;
      if (row < M) {
#pragma unroll
        for (int j = 0; j < 4; ++j) {
          int col = ccol + j;
          float v = reluf(acc1[i][j] + bias1[col] + addend[(size_t)row * N + col])
                  + reluf(acc2[i][j] + bias2[col]);
          C[(size_t)row * N + col] = v;
          s[j] += v; sq[j] += v * v;
        }
      }
    }
    __syncthreads();
    if (tid < 2 * BN) ((float*)cs)[tid] = 0.f;
    __syncthreads();
#pragma unroll
    for (int j = 0; j < 4; ++j) {
      atomicAdd(&cs[0][tcol * 4 + j], s[j]);
      atomicAdd(&cs[1][tcol * 4 + j], sq[j]);
    }
    __syncthreads();
    if (tid < BN) {
      atomicAdd(&colsum[col0 + tid], cs[0][tid]);
      atomicAdd(&colsum[N + col0 + tid], cs[1][tid]);
    }
  } else {
#pragma unroll
    for (int i = 0; i < 4; ++i) {
      int row = row0 + trow * 4 + i;
      if (row < M) {
#pragma unroll
        for (int j = 0; j < 4; ++j) {
          int col = ccol + j;
          float v = acc1[i][j] + bias1[col];
          if constexpr (EPI == 1) v = reluf(v);
          C[(size_t)row * N + col] = v;
        }
      }
    }
  }
}

// ---------------- BatchNorm apply ----------------
__global__ void bn_apply(float* __restrict__ h, const float* __restrict__ colsum,
                         const float* __restrict__ gamma, const float* __restrict__ beta, int M) {
  size_t idx = (size_t)blockIdx.x * blockDim.x + threadIdx.x;
  if (idx >= (size_t)M * HD) return;
  int c = (int)(idx & (HD - 1));
  float invM = 1.f / (float)M;
  float mu = colsum[c] * invM;
  float var = colsum[HD + c] * invM - mu * mu;
  float inv = rsqrtf(var + 1e-5f);
  h[idx] = (h[idx] - mu) * inv * gamma[c] + beta[c];
}

// ---------------- segment-sum accumulation ----------------
__global__ void seg_accum(const float* __restrict__ h, const int* __restrict__ gid,
                          const int* __restrict__ mid, float* __restrict__ gsum,
                          float* __restrict__ gcnt, float* __restrict__ msum,
                          float* __restrict__ mcnt, int Nn) {
  int node = blockIdx.x * 2 + (threadIdx.x >> 7);
  if (node >= Nn) return;
  int c = threadIdx.x & 127;
  float v = h[(size_t)node * HD + c];
  int g = gid[node], m = mid[node];
  atomicAdd(&gsum[(size_t)g * HD + c], v);
  atomicAdd(&msum[(size_t)m * HD + c], v);
  if (c == 0) { atomicAdd(&gcnt[g], 1.f); atomicAdd(&mcnt[m], 1.f); }
}

__global__ void seg_norm(const float* __restrict__ sum, const float* __restrict__ cnt,
                         float* __restrict__ out, int R) {
  size_t idx = (size_t)blockIdx.x * blockDim.x + threadIdx.x;
  if (idx >= (size_t)R * HD) return;
  int r = (int)(idx >> 7);
  out[idx] = sum[idx] / fmaxf(cnt[r], 1.f);
}

extern "C" void kernel_launch(void* const* d_in, const int* in_sizes, int n_in,
                              void* d_out, int out_size, void* d_ws, size_t ws_size,
                              hipStream_t stream) {
  const float* x0     = (const float*)d_in[0];
  const int*   src    = (const int*)d_in[1];
  const int*   dst    = (const int*)d_in[2];
  const int*   etype  = (const int*)d_in[3];
  const int*   gids   = (const int*)d_in[4];
  const int*   mids   = (const int*)d_in[5];
  const float* W1     = (const float*)d_in[6];
  const float* loopW1 = (const float*)d_in[7];
  const float* b1     = (const float*)d_in[8];
  const float* resW1  = (const float*)d_in[9];
  const float* resb1  = (const float*)d_in[10];
  const float* g1     = (const float*)d_in[11];
  const float* be1    = (const float*)d_in[12];
  const float* W2     = (const float*)d_in[13];
  const float* loopW2 = (const float*)d_in[14];
  const float* b2     = (const float*)d_in[15];
  const float* resW2  = (const float*)d_in[16];
  const float* resb2  = (const float*)d_in[17];
  const float* g2     = (const float*)d_in[18];
  const float* be2    = (const float*)d_in[19];
  const float* featW  = (const float*)d_in[20];   // [512,128]
  const float* featb  = (const float*)d_in[21];
  const float* mW1    = (const float*)d_in[22];   // [512,512]
  const float* mb1    = (const float*)d_in[23];
  const float* mW2    = (const float*)d_in[24];   // [256,512]
  const float* mb2    = (const float*)d_in[25];

  const int N = in_sizes[0] / HD;   // 30000
  const int E = in_sizes[1];        // 90000
  const int NG = 1500, NM = 6001, FFN = 512, OUT2 = 256;
  const int NCH = (E + 63) / 64 + NREL;   // upper bound on padded chunk count

  float* ws = (float*)d_ws;
  size_t off = 0;
  auto alloc = [&](size_t n) { float* p = ws + off; off += (n + 63) & ~((size_t)63); return p; };
  float* agg    = alloc((size_t)N * HD);
  float* h1     = alloc((size_t)N * HD);
  float* h2     = alloc((size_t)N * HD);
  float* lwT1   = alloc(HD * HD);
  float* lwT2   = alloc(HD * HD);
  float* colsum = alloc(2 * HD);
  float* gsum   = alloc((size_t)NG * HD);
  float* gcnt   = alloc(NG);
  float* msum   = alloc((size_t)NM * HD);
  float* mcnt   = alloc(NM);
  int* counts    = (int*)alloc(NREL);
  int* offs      = (int*)alloc(NREL + 1);
  int* cursor    = (int*)alloc(NREL);
  int* chunk_rel = (int*)alloc(NCH);
  int* ssrc      = (int*)alloc((size_t)NCH * 64);
  int* sdst      = (int*)alloc((size_t)NCH * 64);
  float* fbuf = h1;   // dead after layer-2 GEMM -> head intermediate f
  float* obuf = agg;  // dead after layer-2 GEMM -> head intermediate o

  float* out_gf = (float*)d_out;
  float* out_gl = out_gf + (size_t)NG * HD;
  float* out_sb = out_gl + (size_t)NG * OUT2;

  dim3 blk(256);
  dim3 gridDual(HD / BN, (N + BM - 1) / BM);
  int bnBlocks = (int)(((size_t)N * HD + 255) / 256);

  transpose128<<<HD, HD, 0, stream>>>(loopW1, lwT1);
  transpose128<<<HD, HD, 0, stream>>>(loopW2, lwT2);

  // ---- bucket edges by relation (once; reused by both layers) ----
  hipMemsetAsync(counts, 0, NREL * sizeof(int), stream);
  hipMemsetAsync(cursor, 0, NREL * sizeof(int), stream);
  hipMemsetAsync(chunk_rel, 0xFF, NCH * sizeof(int), stream);
  hipMemsetAsync(ssrc, 0xFF, (size_t)NCH * 64 * sizeof(int), stream);
  hipMemsetAsync(sdst, 0xFF, (size_t)NCH * 64 * sizeof(int), stream);
  edge_hist<<<(E + 255) / 256, blk, 0, stream>>>(etype, counts, E);
  rel_offsets<<<1, 64, 0, stream>>>(counts, offs);
  edge_scatter<<<(E + 255) / 256, blk, 0, stream>>>(src, dst, etype, offs, cursor,
                                                    ssrc, sdst, chunk_rel, E);

  // ---------------- layer 1 ----------------
  hipMemsetAsync(agg, 0, (size_t)N * HD * sizeof(float), stream);
  hipMemsetAsync(colsum, 0, 2 * HD * sizeof(float), stream);
  edge_gemm<<<NCH, blk, 0, stream>>>(x0, W1, ssrc, sdst, chunk_rel, agg);
  gemm_nt<true, 2><<<gridDual, blk, 0, stream>>>(x0, lwT1, resW1, b1, resb1, agg, h1, colsum, N, HD, HD);
  bn_apply<<<bnBlocks, blk, 0, stream>>>(h1, colsum, g1, be1, N);

  // ---------------- layer 2 ----------------
  hipMemsetAsync(agg, 0, (size_t)N * HD * sizeof(float), stream);
  hipMemsetAsync(colsum, 0, 2 * HD * sizeof(float), stream);
  edge_gemm<<<NCH, blk, 0, stream>>>(h1, W2, ssrc, sdst, chunk_rel, agg);
  gemm_nt<true, 2><<<gridDual, blk, 0, stream>>>(h1, lwT2, resW2, b2, resb2, agg, h2, colsum, N, HD, HD);
  bn_apply<<<bnBlocks, blk, 0, stream>>>(h2, colsum, g2, be2, N);

  // ---------------- readout ----------------
  hipMemsetAsync(gsum, 0, (size_t)NG * HD * sizeof(float), stream);
  hipMemsetAsync(gcnt, 0, NG * sizeof(float), stream);
  hipMemsetAsync(msum, 0, (size_t)NM * HD * sizeof(float), stream);
  hipMemsetAsync(mcnt, 0, NM * sizeof(float), stream);
  seg_accum<<<(N + 1) / 2, blk, 0, stream>>>(h2, gids, mids, gsum, gcnt, msum, mcnt, N);
  seg_norm<<<(int)(((size_t)NG * HD + 255) / 256), blk, 0, stream>>>(gsum, gcnt, out_gf, NG);
  seg_norm<<<(int)(((size_t)NM * HD + 255) / 256), blk, 0, stream>>>(msum, mcnt, msum, NM);

  auto run_head = [&](const float* in, int M, float* outp) {
    dim3 gA(FFN / BN, (M + BM - 1) / BM);
    gemm_nt<false, 0><<<gA, blk, 0, stream>>>(in, featW, nullptr, featb, nullptr, nullptr, fbuf, nullptr, M, FFN, HD);
    dim3 gB(FFN / BN, (M + BM - 1) / BM);
    gemm_nt<false, 1><<<gB, blk, 0, stream>>>(fbuf, mW1, nullptr, mb1, nullptr, nullptr, obuf, nullptr, M, FFN, FFN);
    dim3 gC(OUT2 / BN, (M + BM - 1) / BM);
    gemm_nt<false, 0><<<gC, blk, 0, stream>>>(obuf, mW2, nullptr, mb2, nullptr, nullptr, outp, nullptr, M, OUT2, FFN);
  };
  run_head(out_gf, NG, out_gl);
  run_head(msum + HD, NM - 1, out_sb);
}

// Round 4
// 506.213 us; speedup vs baseline: 2.6529x; 1.5023x over previous
//
#include <hip/hip_runtime.h>
#include <cstddef>

#define HD 128   // hidden dim
#define NREL 65
#define BM 64
#define BN 64
#define BK 16

__device__ __forceinline__ float reluf(float v) { return v > 0.f ? v : 0.f; }

// ---------------- transpose 128x128 (loopW -> loopW^T) ----------------
__global__ void transpose128(const float* __restrict__ in, float* __restrict__ out) {
  out[(size_t)blockIdx.x * HD + threadIdx.x] = in[(size_t)threadIdx.x * HD + blockIdx.x];
}

// ---------------- edge bucketing by relation (LDS-aggregated counting sort) ----------------
__global__ void edge_hist(const int* __restrict__ et, int* __restrict__ counts, int E) {
  __shared__ int lc[NREL];
  int tid = threadIdx.x;
  if (tid < NREL) lc[tid] = 0;
  __syncthreads();
  int i = blockIdx.x * blockDim.x + tid;
  if (i < E) atomicAdd(&lc[et[i]], 1);
  __syncthreads();
  if (tid < NREL && lc[tid] > 0) atomicAdd(&counts[tid], lc[tid]);
}

__global__ void rel_offsets(const int* __restrict__ counts, int* __restrict__ offs) {
  if (threadIdx.x == 0 && blockIdx.x == 0) {
    int o = 0;
    for (int r = 0; r < NREL; ++r) { offs[r] = o; o += (counts[r] + 63) & ~63; }
    offs[NREL] = o;
  }
}

__global__ void edge_scatter(const int* __restrict__ src, const int* __restrict__ dst,
                             const int* __restrict__ et, const int* __restrict__ offs,
                             int* __restrict__ cursor, int* __restrict__ ssrc,
                             int* __restrict__ sdst, int* __restrict__ chunk_rel, int E) {
  __shared__ int lc[NREL];
  __shared__ int lbase[NREL];
  int tid = threadIdx.x;
  if (tid < NREL) lc[tid] = 0;
  __syncthreads();
  int i = blockIdx.x * blockDim.x + tid;
  int r = -1, lrank = 0;
  if (i < E) { r = et[i]; lrank = atomicAdd(&lc[r], 1); }
  __syncthreads();
  if (tid < NREL && lc[tid] > 0) lbase[tid] = atomicAdd(&cursor[tid], lc[tid]);
  __syncthreads();
  if (i < E) {
    int slot = offs[r] + lbase[r] + lrank;
    ssrc[slot] = src[i];
    sdst[slot] = dst[i];
    chunk_rel[slot >> 6] = r;   // 64-aligned buckets: all writers of a chunk agree
  }
}

// ---------------- edge message GEMM: one block per 64-edge chunk (single relation) ----------------
// msg[64,128] = Xg[64,128] @ W[r][128,128]; coalesced atomic scatter-add rows into agg[dst].
__global__ __launch_bounds__(256) void edge_gemm(
    const float* __restrict__ x, const float* __restrict__ W,
    const int* __restrict__ ssrc, const int* __restrict__ sdst,
    const int* __restrict__ chunk_rel, float* __restrict__ agg) {
  int chunk = blockIdx.x;
  int rel = chunk_rel[chunk];
  if (rel < 0) return;                       // empty / all-pad chunk

  __shared__ __align__(16) float As[32][68];     // [k][edge], pad->writes <=2-way, 16B rows
  __shared__ __align__(16) float Bs[32][132];    // [k][out], linear-staged, 16B rows
  __shared__ int dsts[64];

  int tid = threadIdx.x;
  int base = chunk * 64;
  if (tid < 64) dsts[tid] = sdst[base + tid];

  // A staging: edge-per-lane, k-group per 64-thread wave
  int edge = tid & 63;
  int wk = tid >> 6;                    // 0..3 -> k sub-range wk*8..wk*8+7
  int srow = ssrc[base + edge];         // -1 for pad slots (dst guard drops them)
  const float* xr = x + (size_t)(srow >= 0 ? srow : 0) * HD;

  const float* Wb = W + (size_t)rel * HD * HD;

  int trow = tid >> 4;                  // 0..15 (4 rows each)
  int tcol = tid & 15;                  // 0..15 (cols tcol*4.. and 64+tcol*4..)
  float acc[4][8] = {};

  for (int k0 = 0; k0 < HD; k0 += 32) {
    // stage A (gathered x rows; transpose to [k][edge])
    {
      float4 va = *(const float4*)(xr + k0 + wk * 8);
      float4 vb = *(const float4*)(xr + k0 + wk * 8 + 4);
      int kb = wk * 8;
      As[kb + 0][edge] = va.x; As[kb + 1][edge] = va.y;
      As[kb + 2][edge] = va.z; As[kb + 3][edge] = va.w;
      As[kb + 4][edge] = vb.x; As[kb + 5][edge] = vb.y;
      As[kb + 6][edge] = vb.z; As[kb + 7][edge] = vb.w;
    }
    // stage B linearly: lane i -> flat 16B chunk i (coalesced global, conflict-free LDS)
#pragma unroll
    for (int pass = 0; pass < 4; ++pass) {
      int idx = pass * 1024 + tid * 4;
      int kk2 = idx >> 7, nn = idx & 127;
      *(float4*)&Bs[kk2][nn] = *(const float4*)(Wb + (size_t)(k0 + kk2) * HD + nn);
    }
    __syncthreads();
#pragma unroll
    for (int kk = 0; kk < 32; ++kk) {
      float4 a4 = *(const float4*)&As[kk][trow * 4];
      float4 b0 = *(const float4*)&Bs[kk][tcol * 4];
      float4 b1 = *(const float4*)&Bs[kk][64 + tcol * 4];
      float a[4] = {a4.x, a4.y, a4.z, a4.w};
      float b[8] = {b0.x, b0.y, b0.z, b0.w, b1.x, b1.y, b1.z, b1.w};
#pragma unroll
      for (int i = 0; i < 4; ++i)
#pragma unroll
        for (int j = 0; j < 8; ++j) acc[i][j] += a[i] * b[j];
    }
    __syncthreads();
  }

  // epilogue: stage msg rows into Bs (two 32-row halves), wave-coalesced atomics
  for (int h = 0; h < 2; ++h) {
    __syncthreads();
    if ((trow >> 3) == h) {
      int rbase = trow * 4 - h * 32;
#pragma unroll
      for (int i = 0; i < 4; ++i) {
        *(float4*)&Bs[rbase + i][tcol * 4]      = *(float4*)&acc[i][0];
        *(float4*)&Bs[rbase + i][64 + tcol * 4] = *(float4*)&acc[i][4];
      }
    }
    __syncthreads();
#pragma unroll
    for (int it = 0; it < 16; ++it) {
      int row = it * 2 + (tid >> 7);        // 0..31
      int col = tid & 127;                  // wave = 64 consecutive cols of one row
      int d = dsts[h * 32 + row];
      if (d >= 0) atomicAdd(&agg[(size_t)d * HD + col], Bs[row][col]);
    }
  }
}

// ---------------- generic NT GEMM: C[m,n] = epi( sum_k A[m,k]*B[n,k] ) ----------------
template<bool DUAL, int EPI>
__global__ __launch_bounds__(256) void gemm_nt(
    const float* __restrict__ A, const float* __restrict__ B1t, const float* __restrict__ B2t,
    const float* __restrict__ bias1, const float* __restrict__ bias2,
    const float* __restrict__ addend, float* __restrict__ C, float* __restrict__ colsum,
    int M, int N, int K) {
  __shared__ __align__(16) float As[BK][BM];
  __shared__ __align__(16) float B1s[BK][BN];
  __shared__ __align__(16) float B2s[BK][BN];
  __shared__ float cs[2][BN];

  int tid = threadIdx.x;
  int trow = tid >> 4;
  int tcol = tid & 15;
  int row0 = blockIdx.y * BM;
  int col0 = blockIdx.x * BN;
  int lr = tid >> 2;
  int lk = (tid & 3) * 4;

  float acc1[4][4] = {};
  float acc2[4][4] = {};

  for (int k0 = 0; k0 < K; k0 += BK) {
    {
      int gr = row0 + lr;
      float4 v = make_float4(0.f, 0.f, 0.f, 0.f);
      if (gr < M) v = *(const float4*)&A[(size_t)gr * K + k0 + lk];
      As[lk + 0][lr] = v.x; As[lk + 1][lr] = v.y; As[lk + 2][lr] = v.z; As[lk + 3][lr] = v.w;
    }
    {
      int gn = col0 + lr;
      float4 v = *(const float4*)&B1t[(size_t)gn * K + k0 + lk];
      B1s[lk + 0][lr] = v.x; B1s[lk + 1][lr] = v.y; B1s[lk + 2][lr] = v.z; B1s[lk + 3][lr] = v.w;
      if constexpr (DUAL) {
        float4 w = *(const float4*)&B2t[(size_t)gn * K + k0 + lk];
        B2s[lk + 0][lr] = w.x; B2s[lk + 1][lr] = w.y; B2s[lk + 2][lr] = w.z; B2s[lk + 3][lr] = w.w;
      }
    }
    __syncthreads();
#pragma unroll
    for (int kk = 0; kk < BK; ++kk) {
      float4 a4 = *(const float4*)&As[kk][trow * 4];
      float4 b4 = *(const float4*)&B1s[kk][tcol * 4];
      float a[4] = {a4.x, a4.y, a4.z, a4.w};
      float b[4] = {b4.x, b4.y, b4.z, b4.w};
#pragma unroll
      for (int i = 0; i < 4; ++i)
#pragma unroll
        for (int j = 0; j < 4; ++j) acc1[i][j] += a[i] * b[j];
      if constexpr (DUAL) {
        float4 c4 = *(const float4*)&B2s[kk][tcol * 4];
        float c[4] = {c4.x, c4.y, c4.z, c4.w};
#pragma unroll
        for (int i = 0; i < 4; ++i)
#pragma unroll
          for (int j = 0; j < 4; ++j) acc2[i][j] += a[i] * c[j];
      }
    }
    __syncthreads();
  }

  int ccol = col0 + tcol * 4;
  if constexpr (EPI == 2) {
    float s[4] = {0, 0, 0, 0}, sq[4] = {0, 0, 0, 0};
#pragma unroll
    for (int i = 0; i < 4; ++i) {
      int row = row0 + trow * 4 + i;
      if (row < M) {
#pragma unroll
        for (int j = 0; j < 4; ++j) {
          int col = ccol + j;
          float v = reluf(acc1[i][j] + bias1[col] + addend[(size_t)row * N + col])
                  + reluf(acc2[i][j] + bias2[col]);
          C[(size_t)row * N + col] = v;
          s[j] += v; sq[j] += v * v;
        }
      }
    }
    __syncthreads();
    if (tid < 2 * BN) ((float*)cs)[tid] = 0.f;
    __syncthreads();
#pragma unroll
    for (int j = 0; j < 4; ++j) {
      atomicAdd(&cs[0][tcol * 4 + j], s[j]);
      atomicAdd(&cs[1][tcol * 4 + j], sq[j]);
    }
    __syncthreads();
    if (tid < BN) {
      atomicAdd(&colsum[col0 + tid], cs[0][tid]);
      atomicAdd(&colsum[N + col0 + tid], cs[1][tid]);
    }
  } else {
#pragma unroll
    for (int i = 0; i < 4; ++i) {
      int row = row0 + trow * 4 + i;
      if (row < M) {
#pragma unroll
        for (int j = 0; j < 4; ++j) {
          int col = ccol + j;
          float v = acc1[i][j] + bias1[col];
          if constexpr (EPI == 1) v = reluf(v);
          C[(size_t)row * N + col] = v;
        }
      }
    }
  }
}

// ---------------- BatchNorm apply ----------------
__global__ void bn_apply(float* __restrict__ h, const float* __restrict__ colsum,
                         const float* __restrict__ gamma, const float* __restrict__ beta, int M) {
  size_t idx = (size_t)blockIdx.x * blockDim.x + threadIdx.x;
  if (idx >= (size_t)M * HD) return;
  int c = (int)(idx & (HD - 1));
  float invM = 1.f / (float)M;
  float mu = colsum[c] * invM;
  float var = colsum[HD + c] * invM - mu * mu;
  float inv = rsqrtf(var + 1e-5f);
  h[idx] = (h[idx] - mu) * inv * gamma[c] + beta[c];
}

// ---------------- segment-sum accumulation ----------------
__global__ void seg_accum(const float* __restrict__ h, const int* __restrict__ gid,
                          const int* __restrict__ mid, float* __restrict__ gsum,
                          float* __restrict__ gcnt, float* __restrict__ msum,
                          float* __restrict__ mcnt, int Nn) {
  int node = blockIdx.x * 2 + (threadIdx.x >> 7);
  if (node >= Nn) return;
  int c = threadIdx.x & 127;
  float v = h[(size_t)node * HD + c];
  int g = gid[node], m = mid[node];
  atomicAdd(&gsum[(size_t)g * HD + c], v);
  atomicAdd(&msum[(size_t)m * HD + c], v);
  if (c == 0) { atomicAdd(&gcnt[g], 1.f); atomicAdd(&mcnt[m], 1.f); }
}

__global__ void seg_norm(const float* __restrict__ sum, const float* __restrict__ cnt,
                         float* __restrict__ out, int R) {
  size_t idx = (size_t)blockIdx.x * blockDim.x + threadIdx.x;
  if (idx >= (size_t)R * HD) return;
  int r = (int)(idx >> 7);
  out[idx] = sum[idx] / fmaxf(cnt[r], 1.f);
}

extern "C" void kernel_launch(void* const* d_in, const int* in_sizes, int n_in,
                              void* d_out, int out_size, void* d_ws, size_t ws_size,
                              hipStream_t stream) {
  const float* x0     = (const float*)d_in[0];
  const int*   src    = (const int*)d_in[1];
  const int*   dst    = (const int*)d_in[2];
  const int*   etype  = (const int*)d_in[3];
  const int*   gids   = (const int*)d_in[4];
  const int*   mids   = (const int*)d_in[5];
  const float* W1     = (const float*)d_in[6];
  const float* loopW1 = (const float*)d_in[7];
  const float* b1     = (const float*)d_in[8];
  const float* resW1  = (const float*)d_in[9];
  const float* resb1  = (const float*)d_in[10];
  const float* g1     = (const float*)d_in[11];
  const float* be1    = (const float*)d_in[12];
  const float* W2     = (const float*)d_in[13];
  const float* loopW2 = (const float*)d_in[14];
  const float* b2     = (const float*)d_in[15];
  const float* resW2  = (const float*)d_in[16];
  const float* resb2  = (const float*)d_in[17];
  const float* g2     = (const float*)d_in[18];
  const float* be2    = (const float*)d_in[19];
  const float* featW  = (const float*)d_in[20];   // [512,128]
  const float* featb  = (const float*)d_in[21];
  const float* mW1    = (const float*)d_in[22];   // [512,512]
  const float* mb1    = (const float*)d_in[23];
  const float* mW2    = (const float*)d_in[24];   // [256,512]
  const float* mb2    = (const float*)d_in[25];

  const int N = in_sizes[0] / HD;   // 30000
  const int E = in_sizes[1];        // 90000
  const int NG = 1500, NM = 6001, FFN = 512, OUT2 = 256;
  const int NCH = (E + 63) / 64 + NREL;   // upper bound on padded chunk count

  float* ws = (float*)d_ws;
  size_t off = 0;
  auto alloc = [&](size_t n) { float* p = ws + off; off += (n + 63) & ~((size_t)63); return p; };
  float* agg    = alloc((size_t)N * HD);
  float* h1     = alloc((size_t)N * HD);
  float* h2     = alloc((size_t)N * HD);
  float* lwT1   = alloc(HD * HD);
  float* lwT2   = alloc(HD * HD);
  float* colsum = alloc(2 * HD);
  float* gsum   = alloc((size_t)NG * HD);
  float* gcnt   = alloc(NG);
  float* msum   = alloc((size_t)NM * HD);
  float* mcnt   = alloc(NM);
  int* counts    = (int*)alloc(NREL);
  int* offs      = (int*)alloc(NREL + 1);
  int* cursor    = (int*)alloc(NREL);
  int* chunk_rel = (int*)alloc(NCH);
  int* ssrc      = (int*)alloc((size_t)NCH * 64);
  int* sdst      = (int*)alloc((size_t)NCH * 64);
  float* fbuf = h1;   // dead after layer-2 GEMM -> head intermediate f
  float* obuf = agg;  // dead after layer-2 GEMM -> head intermediate o

  float* out_gf = (float*)d_out;
  float* out_gl = out_gf + (size_t)NG * HD;
  float* out_sb = out_gl + (size_t)NG * OUT2;

  dim3 blk(256);
  dim3 gridDual(HD / BN, (N + BM - 1) / BM);
  int bnBlocks = (int)(((size_t)N * HD + 255) / 256);

  transpose128<<<HD, HD, 0, stream>>>(loopW1, lwT1);
  transpose128<<<HD, HD, 0, stream>>>(loopW2, lwT2);

  // ---- bucket edges by relation (once; reused by both layers) ----
  hipMemsetAsync(counts, 0, NREL * sizeof(int), stream);
  hipMemsetAsync(cursor, 0, NREL * sizeof(int), stream);
  hipMemsetAsync(chunk_rel, 0xFF, NCH * sizeof(int), stream);
  hipMemsetAsync(ssrc, 0xFF, (size_t)NCH * 64 * sizeof(int), stream);
  hipMemsetAsync(sdst, 0xFF, (size_t)NCH * 64 * sizeof(int), stream);
  edge_hist<<<(E + 255) / 256, blk, 0, stream>>>(etype, counts, E);
  rel_offsets<<<1, 64, 0, stream>>>(counts, offs);
  edge_scatter<<<(E + 255) / 256, blk, 0, stream>>>(src, dst, etype, offs, cursor,
                                                    ssrc, sdst, chunk_rel, E);

  // ---------------- layer 1 ----------------
  hipMemsetAsync(agg, 0, (size_t)N * HD * sizeof(float), stream);
  hipMemsetAsync(colsum, 0, 2 * HD * sizeof(float), stream);
  edge_gemm<<<NCH, blk, 0, stream>>>(x0, W1, ssrc, sdst, chunk_rel, agg);
  gemm_nt<true, 2><<<gridDual, blk, 0, stream>>>(x0, lwT1, resW1, b1, resb1, agg, h1, colsum, N, HD, HD);
  bn_apply<<<bnBlocks, blk, 0, stream>>>(h1, colsum, g1, be1, N);

  // ---------------- layer 2 ----------------
  hipMemsetAsync(agg, 0, (size_t)N * HD * sizeof(float), stream);
  hipMemsetAsync(colsum, 0, 2 * HD * sizeof(float), stream);
  edge_gemm<<<NCH, blk, 0, stream>>>(h1, W2, ssrc, sdst, chunk_rel, agg);
  gemm_nt<true, 2><<<gridDual, blk, 0, stream>>>(h1, lwT2, resW2, b2, resb2, agg, h2, colsum, N, HD, HD);
  bn_apply<<<bnBlocks, blk, 0, stream>>>(h2, colsum, g2, be2, N);

  // ---------------- readout ----------------
  hipMemsetAsync(gsum, 0, (size_t)NG * HD * sizeof(float), stream);
  hipMemsetAsync(gcnt, 0, NG * sizeof(float), stream);
  hipMemsetAsync(msum, 0, (size_t)NM * HD * sizeof(float), stream);
  hipMemsetAsync(mcnt, 0, NM * sizeof(float), stream);
  seg_accum<<<(N + 1) / 2, blk, 0, stream>>>(h2, gids, mids, gsum, gcnt, msum, mcnt, N);
  seg_norm<<<(int)(((size_t)NG * HD + 255) / 256), blk, 0, stream>>>(gsum, gcnt, out_gf, NG);
  seg_norm<<<(int)(((size_t)NM * HD + 255) / 256), blk, 0, stream>>>(msum, mcnt, msum, NM);

  auto run_head = [&](const float* in, int M, float* outp) {
    dim3 gA(FFN / BN, (M + BM - 1) / BM);
    gemm_nt<false, 0><<<gA, blk, 0, stream>>>(in, featW, nullptr, featb, nullptr, nullptr, fbuf, nullptr, M, FFN, HD);
    dim3 gB(FFN / BN, (M + BM - 1) / BM);
    gemm_nt<false, 1><<<gB, blk, 0, stream>>>(fbuf, mW1, nullptr, mb1, nullptr, nullptr, obuf, nullptr, M, FFN, FFN);
    dim3 gC(OUT2 / BN, (M + BM - 1) / BM);
    gemm_nt<false, 0><<<gC, blk, 0, stream>>>(obuf, mW2, nullptr, mb2, nullptr, nullptr, outp, nullptr, M, OUT2, FFN);
  };
  run_head(out_gf, NG, out_gl);
  run_head(msum + HD, NM - 1, out_sb);
}

// Round 5
// 327.967 us; speedup vs baseline: 4.0948x; 1.5435x over previous
//
#include <hip/hip_runtime.h>
#include <cstddef>

#define HD 128   // hidden dim
#define NREL 65

typedef __attribute__((ext_vector_type(8))) short bf16x8;   // 8 bf16 = 4 VGPRs (MFMA A/B frag)
typedef __attribute__((ext_vector_type(4))) float f32x4;    // MFMA C/D frag
#define MFMA_BF16(a, b, c) __builtin_amdgcn_mfma_f32_16x16x32_bf16(a, b, c, 0, 0, 0)

__device__ __forceinline__ unsigned short f2bf(float f) {   // RNE f32->bf16
  unsigned int u = __float_as_uint(f);
  u += 0x7FFFu + ((u >> 16) & 1u);
  return (unsigned short)(u >> 16);
}
__device__ __forceinline__ float reluf(float v) { return v > 0.f ? v : 0.f; }

// ---------------- f32 -> bf16 cast (vectorized, count % 4 == 0) ----------------
__global__ void cast_bf16(const float* __restrict__ in, unsigned short* __restrict__ out, int n4) {
  int i = blockIdx.x * blockDim.x + threadIdx.x;
  if (i >= n4) return;
  float4 v = ((const float4*)in)[i];
  ushort4 o;
  o.x = f2bf(v.x); o.y = f2bf(v.y); o.z = f2bf(v.z); o.w = f2bf(v.w);
  ((ushort4*)out)[i] = o;
}

// ---------------- 128x128 transpose + cast: out[n][k] = bf16(in[k][n]) ----------------
// grid (4, 4, R); block 256 (= 32x8)
__global__ void transcast128(const float* __restrict__ in, unsigned short* __restrict__ out) {
  __shared__ float t[32][33];
  size_t base = (size_t)blockIdx.z * HD * HD;
  int k0 = blockIdx.x * 32, n0 = blockIdx.y * 32;
  int tx = threadIdx.x & 31, ty = threadIdx.x >> 5;
#pragma unroll
  for (int it = 0; it < 4; ++it)
    t[ty + it * 8][tx] = in[base + (size_t)(k0 + ty + it * 8) * HD + n0 + tx];
  __syncthreads();
#pragma unroll
  for (int it = 0; it < 4; ++it)
    out[base + (size_t)(n0 + ty + it * 8) * HD + k0 + tx] = f2bf(t[tx][ty + it * 8]);
}

// ---------------- edge bucketing by relation (LDS-aggregated counting sort) ----------------
__global__ void edge_hist(const int* __restrict__ et, int* __restrict__ counts, int E) {
  __shared__ int lc[NREL];
  int tid = threadIdx.x;
  if (tid < NREL) lc[tid] = 0;
  __syncthreads();
  int i = blockIdx.x * blockDim.x + tid;
  if (i < E) atomicAdd(&lc[et[i]], 1);
  __syncthreads();
  if (tid < NREL && lc[tid] > 0) atomicAdd(&counts[tid], lc[tid]);
}

__global__ void rel_offsets(const int* __restrict__ counts, int* __restrict__ offs) {
  __shared__ int lc[NREL];
  int t = threadIdx.x;
  if (t < NREL) lc[t] = (counts[t] + 63) & ~63;
  __syncthreads();
  if (t <= NREL) {
    int o = 0;
    for (int r = 0; r < t; ++r) o += lc[r];
    offs[t] = o;
  }
}

__global__ void edge_scatter(const int* __restrict__ src, const int* __restrict__ dst,
                             const int* __restrict__ et, const int* __restrict__ offs,
                             int* __restrict__ cursor, int* __restrict__ ssrc,
                             int* __restrict__ sdst, int* __restrict__ chunk_rel, int E) {
  __shared__ int lc[NREL];
  __shared__ int lbase[NREL];
  int tid = threadIdx.x;
  if (tid < NREL) lc[tid] = 0;
  __syncthreads();
  int i = blockIdx.x * blockDim.x + tid;
  int r = -1, lrank = 0;
  if (i < E) { r = et[i]; lrank = atomicAdd(&lc[r], 1); }
  __syncthreads();
  if (tid < NREL && lc[tid] > 0) lbase[tid] = atomicAdd(&cursor[tid], lc[tid]);
  __syncthreads();
  if (i < E) {
    int slot = offs[r] + lbase[r] + lrank;
    ssrc[slot] = src[i];
    sdst[slot] = dst[i];
    chunk_rel[slot >> 6] = r;   // 64-aligned buckets: all writers of a chunk agree
  }
}

// ---------------- edge message GEMM (MFMA bf16): one block per 64-edge chunk ----------------
// msg[64,128] = Xg[64,128] @ W[r]; Wt is pre-transposed [r][n][k] bf16.
__global__ __launch_bounds__(256) void edge_gemm_mfma(
    const unsigned short* __restrict__ xb, const unsigned short* __restrict__ Wt,
    const int* __restrict__ ssrc, const int* __restrict__ sdst,
    const int* __restrict__ chunk_rel, float* __restrict__ agg) {
  int chunk = blockIdx.x;
  int rel = chunk_rel[chunk];
  if (rel < 0) return;

  __shared__ __align__(16) unsigned short Ws[HD][136];  // pad->16B rows, 2-way banks
  __shared__ int dsts[64];

  int tid = threadIdx.x;
  if (tid < 64) dsts[tid] = sdst[chunk * 64 + tid];

  // stage W^T[rel] (32KB) linearly, coalesced
  const unsigned short* Wr = Wt + (size_t)rel * HD * HD;
#pragma unroll
  for (int it = 0; it < 8; ++it) {
    int idx = it * 2048 + tid * 8;
    *(bf16x8*)&Ws[idx >> 7][idx & 127] = *(const bf16x8*)(Wr + idx);
  }

  int lane = tid & 63, w = tid >> 6;
  int l15 = lane & 15, kg = lane >> 4;
  // A frags in registers: wave w owns edges w*16..w*16+15; lane&15 = edge row, kg = k-group
  int srow = ssrc[chunk * 64 + w * 16 + l15];
  bf16x8 afr[4];
  const bf16x8 zb = {0, 0, 0, 0, 0, 0, 0, 0};
  if (srow >= 0) {
    const unsigned short* xr = xb + (size_t)srow * HD + kg * 8;
#pragma unroll
    for (int t = 0; t < 4; ++t) afr[t] = *(const bf16x8*)(xr + t * 32);
  } else {
#pragma unroll
    for (int t = 0; t < 4; ++t) afr[t] = zb;
  }
  __syncthreads();

  f32x4 acc[8];
  const f32x4 zf = {0.f, 0.f, 0.f, 0.f};
#pragma unroll
  for (int c = 0; c < 8; ++c) acc[c] = zf;
#pragma unroll
  for (int t = 0; t < 4; ++t)
#pragma unroll
    for (int c = 0; c < 8; ++c) {
      bf16x8 bfr = *(const bf16x8*)&Ws[c * 16 + l15][t * 32 + kg * 8];
      acc[c] = MFMA_BF16(afr[t], bfr, acc[c]);
    }

  // D: row(edge) = kg*4 + reg, col = c*16 + l15 -> quarter-wave-coalesced atomics
#pragma unroll
  for (int reg = 0; reg < 4; ++reg) {
    int d = dsts[w * 16 + kg * 4 + reg];
    if (d >= 0) {
      float* ap = agg + (size_t)d * HD + l15;
#pragma unroll
      for (int c = 0; c < 8; ++c) atomicAdd(ap + c * 16, acc[c][reg]);
    }
  }
}

// ---------------- generic NT GEMM (MFMA bf16): C = epi( A[M,K] @ B[N,K]^T ) ----------------
// 64x64 tile, 4 waves (2x2), each wave 32x32. EPI 0: +bias; 1: relu(+bias);
// 2 (DUAL): relu(acc1+b1+addend)+relu(acc2+b2), f32 C + BN colsum/colsumsq atomics.
template<bool DUAL, int EPI, bool OBF16>
__global__ __launch_bounds__(256) void gemm_mfma(
    const unsigned short* __restrict__ A, const unsigned short* __restrict__ B1,
    const unsigned short* __restrict__ B2, const float* __restrict__ bias1,
    const float* __restrict__ bias2, const float* __restrict__ addend,
    float* __restrict__ Cf, unsigned short* __restrict__ Cb,
    float* __restrict__ colsum, int M, int N, int K) {
  __shared__ __align__(16) unsigned short As[64][40];
  __shared__ __align__(16) unsigned short B1s[64][40];
  __shared__ __align__(16) unsigned short B2s[DUAL ? 64 : 1][40];
  __shared__ float cs[2][64];

  int tid = threadIdx.x;
  int lane = tid & 63, w = tid >> 6;
  int wr = w >> 1, wc = w & 1;
  int l15 = lane & 15, kg = lane >> 4;
  int row0 = blockIdx.y * 64, col0 = blockIdx.x * 64;
  int srow = tid >> 2, skc = (tid & 3) * 8;

  f32x4 acc1[2][2], acc2[2][2];
  const f32x4 zf = {0.f, 0.f, 0.f, 0.f};
  const bf16x8 zb = {0, 0, 0, 0, 0, 0, 0, 0};
#pragma unroll
  for (int i = 0; i < 2; ++i)
#pragma unroll
    for (int j = 0; j < 2; ++j) { acc1[i][j] = zf; acc2[i][j] = zf; }

  for (int k0 = 0; k0 < K; k0 += 32) {
    {
      int gr = row0 + srow;
      bf16x8 v = zb;
      if (gr < M) v = *(const bf16x8*)(A + (size_t)gr * K + k0 + skc);
      *(bf16x8*)&As[srow][skc] = v;
      *(bf16x8*)&B1s[srow][skc] = *(const bf16x8*)(B1 + (size_t)(col0 + srow) * K + k0 + skc);
      if constexpr (DUAL)
        *(bf16x8*)&B2s[srow][skc] = *(const bf16x8*)(B2 + (size_t)(col0 + srow) * K + k0 + skc);
    }
    __syncthreads();
    bf16x8 af[2], b1f[2];
#pragma unroll
    for (int i = 0; i < 2; ++i) af[i] = *(const bf16x8*)&As[wr * 32 + i * 16 + l15][kg * 8];
#pragma unroll
    for (int j = 0; j < 2; ++j) b1f[j] = *(const bf16x8*)&B1s[wc * 32 + j * 16 + l15][kg * 8];
#pragma unroll
    for (int i = 0; i < 2; ++i)
#pragma unroll
      for (int j = 0; j < 2; ++j) acc1[i][j] = MFMA_BF16(af[i], b1f[j], acc1[i][j]);
    if constexpr (DUAL) {
      bf16x8 b2f[2];
#pragma unroll
      for (int j = 0; j < 2; ++j) b2f[j] = *(const bf16x8*)&B2s[wc * 32 + j * 16 + l15][kg * 8];
#pragma unroll
      for (int i = 0; i < 2; ++i)
#pragma unroll
        for (int j = 0; j < 2; ++j) acc2[i][j] = MFMA_BF16(af[i], b2f[j], acc2[i][j]);
    }
    __syncthreads();
  }

  // epilogue. D: col = (wc*32 + j*16 + l15), row = (wr*32 + i*16 + kg*4 + reg)
  float s[2] = {0.f, 0.f}, sq[2] = {0.f, 0.f};
#pragma unroll
  for (int i = 0; i < 2; ++i)
#pragma unroll
    for (int reg = 0; reg < 4; ++reg) {
      int row = row0 + wr * 32 + i * 16 + kg * 4 + reg;
      if (row < M) {
#pragma unroll
        for (int j = 0; j < 2; ++j) {
          int col = col0 + wc * 32 + j * 16 + l15;
          float v = acc1[i][j][reg];
          if constexpr (EPI == 2) {
            v = reluf(v + bias1[col] + addend[(size_t)row * N + col])
              + reluf(acc2[i][j][reg] + bias2[col]);
            Cf[(size_t)row * N + col] = v;
            s[j] += v; sq[j] += v * v;
          } else {
            v += bias1[col];
            if constexpr (EPI == 1) v = reluf(v);
            if constexpr (OBF16) Cb[(size_t)row * N + col] = f2bf(v);
            else Cf[(size_t)row * N + col] = v;
          }
        }
      }
    }
  if constexpr (EPI == 2) {
    __syncthreads();
    if (tid < 128) ((float*)cs)[tid] = 0.f;
    __syncthreads();
#pragma unroll
    for (int j = 0; j < 2; ++j) {
      int lc = wc * 32 + j * 16 + l15;
      atomicAdd(&cs[0][lc], s[j]);
      atomicAdd(&cs[1][lc], sq[j]);
    }
    __syncthreads();
    if (tid < 64) {
      atomicAdd(&colsum[col0 + tid], cs[0][tid]);
      atomicAdd(&colsum[HD + col0 + tid], cs[1][tid]);
    }
  }
}

// ---------------- BatchNorm apply; optional f32 and bf16 outputs ----------------
template<bool WF32, bool WBF16>
__global__ void bn_apply2(float* __restrict__ h, unsigned short* __restrict__ hb,
                          const float* __restrict__ colsum, const float* __restrict__ gamma,
                          const float* __restrict__ beta, int M) {
  int i = blockIdx.x * blockDim.x + threadIdx.x;
  if (i >= M * (HD / 4)) return;
  int c0 = (i & 31) * 4;
  float invM = 1.f / (float)M;
  float4 v = ((const float4*)h)[i];
  float r[4] = {v.x, v.y, v.z, v.w};
#pragma unroll
  for (int j = 0; j < 4; ++j) {
    int c = c0 + j;
    float mu = colsum[c] * invM;
    float var = colsum[HD + c] * invM - mu * mu;
    r[j] = (r[j] - mu) * rsqrtf(var + 1e-5f) * gamma[c] + beta[c];
  }
  if constexpr (WF32) { float4 o = {r[0], r[1], r[2], r[3]}; ((float4*)h)[i] = o; }
  if constexpr (WBF16) {
    ushort4 o;
    o.x = f2bf(r[0]); o.y = f2bf(r[1]); o.z = f2bf(r[2]); o.w = f2bf(r[3]);
    ((ushort4*)hb)[i] = o;
  }
}

// ---------------- segment-sum accumulation ----------------
__global__ void seg_accum(const float* __restrict__ h, const int* __restrict__ gid,
                          const int* __restrict__ mid, float* __restrict__ gsum,
                          float* __restrict__ gcnt, float* __restrict__ msum,
                          float* __restrict__ mcnt, int Nn) {
  int node = blockIdx.x * 2 + (threadIdx.x >> 7);
  if (node >= Nn) return;
  int c = threadIdx.x & 127;
  float v = h[(size_t)node * HD + c];
  int g = gid[node], m = mid[node];
  atomicAdd(&gsum[(size_t)g * HD + c], v);
  atomicAdd(&msum[(size_t)m * HD + c], v);
  if (c == 0) { atomicAdd(&gcnt[g], 1.f); atomicAdd(&mcnt[m], 1.f); }
}

template<bool WF32>
__global__ void seg_norm2(const float* __restrict__ sum, const float* __restrict__ cnt,
                          float* __restrict__ outf, unsigned short* __restrict__ outb, int R) {
  int idx = blockIdx.x * blockDim.x + threadIdx.x;
  if (idx >= R * HD) return;
  int r = idx >> 7;
  float v = sum[idx] / fmaxf(cnt[r], 1.f);
  if constexpr (WF32) outf[idx] = v;
  outb[idx] = f2bf(v);
}

extern "C" void kernel_launch(void* const* d_in, const int* in_sizes, int n_in,
                              void* d_out, int out_size, void* d_ws, size_t ws_size,
                              hipStream_t stream) {
  const float* x0     = (const float*)d_in[0];
  const int*   src    = (const int*)d_in[1];
  const int*   dst    = (const int*)d_in[2];
  const int*   etype  = (const int*)d_in[3];
  const int*   gids   = (const int*)d_in[4];
  const int*   mids   = (const int*)d_in[5];
  const float* W1     = (const float*)d_in[6];
  const float* loopW1 = (const float*)d_in[7];
  const float* b1     = (const float*)d_in[8];
  const float* resW1  = (const float*)d_in[9];
  const float* resb1  = (const float*)d_in[10];
  const float* g1     = (const float*)d_in[11];
  const float* be1    = (const float*)d_in[12];
  const float* W2     = (const float*)d_in[13];
  const float* loopW2 = (const float*)d_in[14];
  const float* b2     = (const float*)d_in[15];
  const float* resW2  = (const float*)d_in[16];
  const float* resb2  = (const float*)d_in[17];
  const float* g2     = (const float*)d_in[18];
  const float* be2    = (const float*)d_in[19];
  const float* featW  = (const float*)d_in[20];   // [512,128]
  const float* featb  = (const float*)d_in[21];
  const float* mW1    = (const float*)d_in[22];   // [512,512]
  const float* mb1    = (const float*)d_in[23];
  const float* mW2    = (const float*)d_in[24];   // [256,512]
  const float* mb2    = (const float*)d_in[25];

  const int N = in_sizes[0] / HD;   // 30000
  const int E = in_sizes[1];        // 90000
  const int NG = 1500, NM = 6001, FFN = 512, OUT2 = 256;
  const int NCH = (E + 63) / 64 + NREL;
  const int NHD = N * HD;

  float* ws = (float*)d_ws;
  size_t off = 0;
  auto alloc = [&](size_t n) { float* p = ws + off; off += (n + 63) & ~((size_t)63); return p; };
  float* agg   = alloc(NHD);                 // f32 edge aggregate; later head intermediates
  float* hbuf  = alloc(NHD);                 // h1 f32 then h2 f32
  unsigned short* xb    = (unsigned short*)alloc(NHD / 2);  // x bf16, then h1 bf16
  unsigned short* W1tb  = (unsigned short*)alloc((size_t)NREL * HD * HD / 2);
  unsigned short* W2tb  = (unsigned short*)alloc((size_t)NREL * HD * HD / 2);
  unsigned short* lwT1b = (unsigned short*)alloc(HD * HD / 2);
  unsigned short* lwT2b = (unsigned short*)alloc(HD * HD / 2);
  unsigned short* rW1b  = (unsigned short*)alloc(HD * HD / 2);
  unsigned short* rW2b  = (unsigned short*)alloc(HD * HD / 2);
  unsigned short* featWb= (unsigned short*)alloc(FFN * HD / 2);
  unsigned short* mW1b  = (unsigned short*)alloc(FFN * FFN / 2);
  unsigned short* mW2b  = (unsigned short*)alloc(OUT2 * FFN / 2);
  float* colsum = alloc(2 * HD);
  float* gsum   = alloc((size_t)NG * HD);
  float* gcnt   = alloc(NG);
  float* msum   = alloc((size_t)NM * HD);
  float* mcnt   = alloc(NM);
  unsigned short* gfb  = (unsigned short*)alloc((size_t)NG * HD / 2);
  unsigned short* mbuf = (unsigned short*)alloc(((size_t)NM * HD + 63) / 2);
  int* counts    = (int*)alloc(NREL);
  int* offs      = (int*)alloc(NREL + 1);
  int* cursor    = (int*)alloc(NREL);
  int* chunk_rel = (int*)alloc(NCH);
  int* ssrc      = (int*)alloc((size_t)NCH * 64);
  int* sdst      = (int*)alloc((size_t)NCH * 64);
  // head intermediates alias agg (dead after layer-2 dual GEMM)
  unsigned short* fbuf_b = (unsigned short*)agg;             // <= 6000x512 bf16 = 6.1MB
  unsigned short* obuf_b = (unsigned short*)(agg + NHD / 2); // second half of agg

  float* out_gf = (float*)d_out;
  float* out_gl = out_gf + (size_t)NG * HD;
  float* out_sb = out_gl + (size_t)NG * OUT2;

  dim3 blk(256);

  // ---- one-time weight/feature casts ----
  cast_bf16<<<(NHD / 4 + 255) / 256, blk, 0, stream>>>(x0, xb, NHD / 4);
  transcast128<<<dim3(4, 4, NREL), blk, 0, stream>>>(W1, W1tb);
  transcast128<<<dim3(4, 4, NREL), blk, 0, stream>>>(W2, W2tb);
  transcast128<<<dim3(4, 4, 1), blk, 0, stream>>>(loopW1, lwT1b);
  transcast128<<<dim3(4, 4, 1), blk, 0, stream>>>(loopW2, lwT2b);
  cast_bf16<<<(HD * HD / 4 + 255) / 256, blk, 0, stream>>>(resW1, rW1b, HD * HD / 4);
  cast_bf16<<<(HD * HD / 4 + 255) / 256, blk, 0, stream>>>(resW2, rW2b, HD * HD / 4);
  cast_bf16<<<(FFN * HD / 4 + 255) / 256, blk, 0, stream>>>(featW, featWb, FFN * HD / 4);
  cast_bf16<<<(FFN * FFN / 4 + 255) / 256, blk, 0, stream>>>(mW1, mW1b, FFN * FFN / 4);
  cast_bf16<<<(OUT2 * FFN / 4 + 255) / 256, blk, 0, stream>>>(mW2, mW2b, OUT2 * FFN / 4);

  // ---- bucket edges by relation (once; reused by both layers) ----
  hipMemsetAsync(counts, 0, NREL * sizeof(int), stream);
  hipMemsetAsync(cursor, 0, NREL * sizeof(int), stream);
  hipMemsetAsync(chunk_rel, 0xFF, NCH * sizeof(int), stream);
  hipMemsetAsync(ssrc, 0xFF, (size_t)NCH * 64 * sizeof(int), stream);
  hipMemsetAsync(sdst, 0xFF, (size_t)NCH * 64 * sizeof(int), stream);
  edge_hist<<<(E + 255) / 256, blk, 0, stream>>>(etype, counts, E);
  rel_offsets<<<1, 128, 0, stream>>>(counts, offs);
  edge_scatter<<<(E + 255) / 256, blk, 0, stream>>>(src, dst, etype, offs, cursor,
                                                    ssrc, sdst, chunk_rel, E);

  dim3 gridDual(HD / 64, (N + 63) / 64);
  int bnBlocks = (N * (HD / 4) + 255) / 256;

  // ---------------- layer 1 ----------------
  hipMemsetAsync(agg, 0, (size_t)NHD * sizeof(float), stream);
  hipMemsetAsync(colsum, 0, 2 * HD * sizeof(float), stream);
  edge_gemm_mfma<<<NCH, blk, 0, stream>>>(xb, W1tb, ssrc, sdst, chunk_rel, agg);
  gemm_mfma<true, 2, false><<<gridDual, blk, 0, stream>>>(
      xb, lwT1b, rW1b, b1, resb1, agg, hbuf, nullptr, colsum, N, HD, HD);
  bn_apply2<false, true><<<bnBlocks, blk, 0, stream>>>(hbuf, xb, colsum, g1, be1, N);  // -> h1 bf16 (reuses xb)

  // ---------------- layer 2 ----------------
  hipMemsetAsync(agg, 0, (size_t)NHD * sizeof(float), stream);
  hipMemsetAsync(colsum, 0, 2 * HD * sizeof(float), stream);
  edge_gemm_mfma<<<NCH, blk, 0, stream>>>(xb, W2tb, ssrc, sdst, chunk_rel, agg);
  gemm_mfma<true, 2, false><<<gridDual, blk, 0, stream>>>(
      xb, lwT2b, rW2b, b2, resb2, agg, hbuf, nullptr, colsum, N, HD, HD);
  bn_apply2<true, false><<<bnBlocks, blk, 0, stream>>>(hbuf, nullptr, colsum, g2, be2, N);  // h2 f32

  // ---------------- readout ----------------
  hipMemsetAsync(gsum, 0, (size_t)NG * HD * sizeof(float), stream);
  hipMemsetAsync(gcnt, 0, NG * sizeof(float), stream);
  hipMemsetAsync(msum, 0, (size_t)NM * HD * sizeof(float), stream);
  hipMemsetAsync(mcnt, 0, NM * sizeof(float), stream);
  seg_accum<<<(N + 1) / 2, blk, 0, stream>>>(hbuf, gids, mids, gsum, gcnt, msum, mcnt, N);
  seg_norm2<true><<<(NG * HD + 255) / 256, blk, 0, stream>>>(gsum, gcnt, out_gf, gfb, NG);
  seg_norm2<false><<<(NM * HD + 255) / 256, blk, 0, stream>>>(msum, mcnt, nullptr, mbuf, NM);

  // head(g): f = g@featW^T + featb ; o = relu(f@mW1^T + mb1) ; out = o@mW2^T + mb2
  auto run_head = [&](const unsigned short* inb, int M, float* outp) {
    dim3 gA(FFN / 64, (M + 63) / 64);
    gemm_mfma<false, 0, true><<<gA, blk, 0, stream>>>(
        inb, featWb, nullptr, featb, nullptr, nullptr, nullptr, fbuf_b, nullptr, M, FFN, HD);
    dim3 gB(FFN / 64, (M + 63) / 64);
    gemm_mfma<false, 1, true><<<gB, blk, 0, stream>>>(
        fbuf_b, mW1b, nullptr, mb1, nullptr, nullptr, nullptr, obuf_b, nullptr, M, FFN, FFN);
    dim3 gC(OUT2 / 64, (M + 63) / 64);
    gemm_mfma<false, 0, false><<<gC, blk, 0, stream>>>(
        obuf_b, mW2b, nullptr, mb2, nullptr, nullptr, outp, nullptr, nullptr, M, OUT2, FFN);
  };
  run_head(gfb, NG, out_gl);
  run_head(mbuf + HD, NM - 1, out_sb);
}

// Round 6
// 304.427 us; speedup vs baseline: 4.4114x; 1.0773x over previous
//
#include <hip/hip_runtime.h>
#include <cstddef>

#define HD 128   // hidden dim
#define NREL 65
#define NPB 32   // nodes per block in seg_accum2

typedef __attribute__((ext_vector_type(8))) short bf16x8;   // 8 bf16 = 4 VGPRs (MFMA A/B frag)
typedef __attribute__((ext_vector_type(4))) float f32x4;    // MFMA C/D frag
#define MFMA_BF16(a, b, c) __builtin_amdgcn_mfma_f32_16x16x32_bf16(a, b, c, 0, 0, 0)

__device__ __forceinline__ unsigned short f2bf(float f) {   // RNE f32->bf16
  unsigned int u = __float_as_uint(f);
  u += 0x7FFFu + ((u >> 16) & 1u);
  return (unsigned short)(u >> 16);
}
__device__ __forceinline__ float reluf(float v) { return v > 0.f ? v : 0.f; }

// ---------------- f32 -> bf16 cast (vectorized, count % 4 == 0) ----------------
__global__ void cast_bf16(const float* __restrict__ in, unsigned short* __restrict__ out, int n4) {
  int i = blockIdx.x * blockDim.x + threadIdx.x;
  if (i >= n4) return;
  float4 v = ((const float4*)in)[i];
  ushort4 o;
  o.x = f2bf(v.x); o.y = f2bf(v.y); o.z = f2bf(v.z); o.w = f2bf(v.w);
  ((ushort4*)out)[i] = o;
}

// ---------------- 128x128 transpose + cast: out[n][k] = bf16(in[k][n]) ----------------
// grid (4, 4, R); block 256 (= 32x8)
__global__ void transcast128(const float* __restrict__ in, unsigned short* __restrict__ out) {
  __shared__ float t[32][33];
  size_t base = (size_t)blockIdx.z * HD * HD;
  int k0 = blockIdx.x * 32, n0 = blockIdx.y * 32;
  int tx = threadIdx.x & 31, ty = threadIdx.x >> 5;
#pragma unroll
  for (int it = 0; it < 4; ++it)
    t[ty + it * 8][tx] = in[base + (size_t)(k0 + ty + it * 8) * HD + n0 + tx];
  __syncthreads();
#pragma unroll
  for (int it = 0; it < 4; ++it)
    out[base + (size_t)(n0 + ty + it * 8) * HD + k0 + tx] = f2bf(t[tx][ty + it * 8]);
}

// ---------------- edge bucketing by relation (LDS-aggregated counting sort) ----------------
__global__ void edge_hist(const int* __restrict__ et, int* __restrict__ counts, int E) {
  __shared__ int lc[NREL];
  int tid = threadIdx.x;
  if (tid < NREL) lc[tid] = 0;
  __syncthreads();
  int i = blockIdx.x * blockDim.x + tid;
  if (i < E) atomicAdd(&lc[et[i]], 1);
  __syncthreads();
  if (tid < NREL && lc[tid] > 0) atomicAdd(&counts[tid], lc[tid]);
}

__global__ void rel_offsets(const int* __restrict__ counts, int* __restrict__ offs) {
  __shared__ int lc[NREL];
  int t = threadIdx.x;
  if (t < NREL) lc[t] = (counts[t] + 63) & ~63;
  __syncthreads();
  if (t <= NREL) {
    int o = 0;
    for (int r = 0; r < t; ++r) o += lc[r];
    offs[t] = o;
  }
}

__global__ void edge_scatter(const int* __restrict__ src, const int* __restrict__ dst,
                             const int* __restrict__ et, const int* __restrict__ offs,
                             int* __restrict__ cursor, int* __restrict__ ssrc,
                             int* __restrict__ sdst, int* __restrict__ chunk_rel, int E) {
  __shared__ int lc[NREL];
  __shared__ int lbase[NREL];
  int tid = threadIdx.x;
  if (tid < NREL) lc[tid] = 0;
  __syncthreads();
  int i = blockIdx.x * blockDim.x + tid;
  int r = -1, lrank = 0;
  if (i < E) { r = et[i]; lrank = atomicAdd(&lc[r], 1); }
  __syncthreads();
  if (tid < NREL && lc[tid] > 0) lbase[tid] = atomicAdd(&cursor[tid], lc[tid]);
  __syncthreads();
  if (i < E) {
    int slot = offs[r] + lbase[r] + lrank;
    ssrc[slot] = src[i];
    sdst[slot] = dst[i];
    chunk_rel[slot >> 6] = r;   // 64-aligned buckets: all writers of a chunk agree
  }
}

// ---------------- edge message GEMM (MFMA bf16): 2 chunks per block ----------------
// msg[64,128] = Xg[64,128] @ W[r]; Wt pre-transposed [r][n][k] bf16. W restaged only on rel change.
__global__ __launch_bounds__(256) void edge_gemm_mfma(
    const unsigned short* __restrict__ xb, const unsigned short* __restrict__ Wt,
    const int* __restrict__ ssrc, const int* __restrict__ sdst,
    const int* __restrict__ chunk_rel, float* __restrict__ agg, int nch) {
  __shared__ __align__(16) unsigned short Ws[HD][136];  // pad -> 16B rows, 2-way banks

  int tid = threadIdx.x;
  int lane = tid & 63, w = tid >> 6;
  int l15 = lane & 15, kg = lane >> 4;
  const bf16x8 zb = {0, 0, 0, 0, 0, 0, 0, 0};
  const f32x4 zf = {0.f, 0.f, 0.f, 0.f};
  int lastRel = -1;

  for (int s = 0; s < 2; ++s) {
    int chunk = blockIdx.x * 2 + s;
    if (chunk >= nch) break;
    int rel = chunk_rel[chunk];            // uniform across block
    if (rel < 0) continue;
    bool restage = (rel != lastRel);
    if (restage) {
      __syncthreads();                     // prior chunk's Ws reads done
      const unsigned short* Wr = Wt + (size_t)rel * HD * HD;
#pragma unroll
      for (int it = 0; it < 8; ++it) {
        int idx = it * 2048 + tid * 8;
        *(bf16x8*)&Ws[idx >> 7][idx & 127] = *(const bf16x8*)(Wr + idx);
      }
      lastRel = rel;
    }
    int base = chunk * 64;
    int srow = ssrc[base + w * 16 + l15];
    bf16x8 afr[4];
    if (srow >= 0) {
      const unsigned short* xr = xb + (size_t)srow * HD + kg * 8;
#pragma unroll
      for (int t = 0; t < 4; ++t) afr[t] = *(const bf16x8*)(xr + t * 32);
    } else {
#pragma unroll
      for (int t = 0; t < 4; ++t) afr[t] = zb;
    }
    if (restage) __syncthreads();          // Ws visible to all waves

    f32x4 acc[8];
#pragma unroll
    for (int c = 0; c < 8; ++c) acc[c] = zf;
#pragma unroll
    for (int t = 0; t < 4; ++t)
#pragma unroll
      for (int c = 0; c < 8; ++c) {
        bf16x8 bfr = *(const bf16x8*)&Ws[c * 16 + l15][t * 32 + kg * 8];
        acc[c] = MFMA_BF16(afr[t], bfr, acc[c]);
      }

    // D: row(edge) = kg*4 + reg, col = c*16 + l15
#pragma unroll
    for (int reg = 0; reg < 4; ++reg) {
      int d = sdst[base + w * 16 + kg * 4 + reg];
      if (d >= 0) {
        float* ap = agg + (size_t)d * HD + l15;
#pragma unroll
        for (int c = 0; c < 8; ++c) atomicAdd(ap + c * 16, acc[c][reg]);
      }
    }
  }
}

// ---------------- generic NT GEMM (MFMA bf16): C = epi( A[M,K] @ B[N,K]^T ) ----------------
// 64x64 tile, 4 waves (2x2), each wave 32x32. EPI 0: +bias; 1: relu(+bias);
// 2 (DUAL): relu(acc1+b1+addend)+relu(acc2+b2), f32 C + BN colsum/colsumsq atomics.
template<bool DUAL, int EPI, bool OBF16>
__global__ __launch_bounds__(256) void gemm_mfma(
    const unsigned short* __restrict__ A, const unsigned short* __restrict__ B1,
    const unsigned short* __restrict__ B2, const float* __restrict__ bias1,
    const float* __restrict__ bias2, const float* __restrict__ addend,
    float* __restrict__ Cf, unsigned short* __restrict__ Cb,
    float* __restrict__ colsum, int M, int N, int K) {
  __shared__ __align__(16) unsigned short As[64][40];
  __shared__ __align__(16) unsigned short B1s[64][40];
  __shared__ __align__(16) unsigned short B2s[DUAL ? 64 : 1][40];
  __shared__ float cs[2][64];

  int tid = threadIdx.x;
  int lane = tid & 63, w = tid >> 6;
  int wr = w >> 1, wc = w & 1;
  int l15 = lane & 15, kg = lane >> 4;
  int row0 = blockIdx.y * 64, col0 = blockIdx.x * 64;
  int srow = tid >> 2, skc = (tid & 3) * 8;

  f32x4 acc1[2][2], acc2[2][2];
  const f32x4 zf = {0.f, 0.f, 0.f, 0.f};
  const bf16x8 zb = {0, 0, 0, 0, 0, 0, 0, 0};
#pragma unroll
  for (int i = 0; i < 2; ++i)
#pragma unroll
    for (int j = 0; j < 2; ++j) { acc1[i][j] = zf; acc2[i][j] = zf; }

  for (int k0 = 0; k0 < K; k0 += 32) {
    {
      int gr = row0 + srow;
      bf16x8 v = zb;
      if (gr < M) v = *(const bf16x8*)(A + (size_t)gr * K + k0 + skc);
      *(bf16x8*)&As[srow][skc] = v;
      *(bf16x8*)&B1s[srow][skc] = *(const bf16x8*)(B1 + (size_t)(col0 + srow) * K + k0 + skc);
      if constexpr (DUAL)
        *(bf16x8*)&B2s[srow][skc] = *(const bf16x8*)(B2 + (size_t)(col0 + srow) * K + k0 + skc);
    }
    __syncthreads();
    bf16x8 af[2], b1f[2];
#pragma unroll
    for (int i = 0; i < 2; ++i) af[i] = *(const bf16x8*)&As[wr * 32 + i * 16 + l15][kg * 8];
#pragma unroll
    for (int j = 0; j < 2; ++j) b1f[j] = *(const bf16x8*)&B1s[wc * 32 + j * 16 + l15][kg * 8];
#pragma unroll
    for (int i = 0; i < 2; ++i)
#pragma unroll
      for (int j = 0; j < 2; ++j) acc1[i][j] = MFMA_BF16(af[i], b1f[j], acc1[i][j]);
    if constexpr (DUAL) {
      bf16x8 b2f[2];
#pragma unroll
      for (int j = 0; j < 2; ++j) b2f[j] = *(const bf16x8*)&B2s[wc * 32 + j * 16 + l15][kg * 8];
#pragma unroll
      for (int i = 0; i < 2; ++i)
#pragma unroll
        for (int j = 0; j < 2; ++j) acc2[i][j] = MFMA_BF16(af[i], b2f[j], acc2[i][j]);
    }
    __syncthreads();
  }

  // epilogue. D: col = (wc*32 + j*16 + l15), row = (wr*32 + i*16 + kg*4 + reg)
  float s[2] = {0.f, 0.f}, sq[2] = {0.f, 0.f};
#pragma unroll
  for (int i = 0; i < 2; ++i)
#pragma unroll
    for (int reg = 0; reg < 4; ++reg) {
      int row = row0 + wr * 32 + i * 16 + kg * 4 + reg;
      if (row < M) {
#pragma unroll
        for (int j = 0; j < 2; ++j) {
          int col = col0 + wc * 32 + j * 16 + l15;
          float v = acc1[i][j][reg];
          if constexpr (EPI == 2) {
            v = reluf(v + bias1[col] + addend[(size_t)row * N + col])
              + reluf(acc2[i][j][reg] + bias2[col]);
            Cf[(size_t)row * N + col] = v;
            s[j] += v; sq[j] += v * v;
          } else {
            v += bias1[col];
            if constexpr (EPI == 1) v = reluf(v);
            if constexpr (OBF16) Cb[(size_t)row * N + col] = f2bf(v);
            else Cf[(size_t)row * N + col] = v;
          }
        }
      }
    }
  if constexpr (EPI == 2) {
    __syncthreads();
    if (tid < 128) ((float*)cs)[tid] = 0.f;
    __syncthreads();
#pragma unroll
    for (int j = 0; j < 2; ++j) {
      int lc = wc * 32 + j * 16 + l15;
      atomicAdd(&cs[0][lc], s[j]);
      atomicAdd(&cs[1][lc], sq[j]);
    }
    __syncthreads();
    if (tid < 64) {
      atomicAdd(&colsum[col0 + tid], cs[0][tid]);
      atomicAdd(&colsum[HD + col0 + tid], cs[1][tid]);
    }
  }
}

// ---------------- BatchNorm apply (layer 1 only: writes bf16 h for next layer) ----------------
__global__ void bn_apply_bf16(const float* __restrict__ h, unsigned short* __restrict__ hb,
                              const float* __restrict__ colsum, const float* __restrict__ gamma,
                              const float* __restrict__ beta, int M) {
  int i = blockIdx.x * blockDim.x + threadIdx.x;
  if (i >= M * (HD / 4)) return;
  int c0 = (i & 31) * 4;
  float invM = 1.f / (float)M;
  float4 v = ((const float4*)h)[i];
  float r[4] = {v.x, v.y, v.z, v.w};
#pragma unroll
  for (int j = 0; j < 4; ++j) {
    int c = c0 + j;
    float mu = colsum[c] * invM;
    float var = colsum[HD + c] * invM - mu * mu;
    r[j] = (r[j] - mu) * rsqrtf(var + 1e-5f) * gamma[c] + beta[c];
  }
  ushort4 o;
  o.x = f2bf(r[0]); o.y = f2bf(r[1]); o.z = f2bf(r[2]); o.w = f2bf(r[3]);
  ((ushort4*)hb)[i] = o;
}

// ---------------- segment-sum: sorted gids run-aggregated; motifs direct ----------------
// Reads PRE-BN h (layer-2 BN folded into seg_norm2 as per-column affine).
__global__ __launch_bounds__(256) void seg_accum2(
    const float* __restrict__ h, const int* __restrict__ gid, const int* __restrict__ mid,
    float* __restrict__ gsum, float* __restrict__ gcnt,
    float* __restrict__ msum, float* __restrict__ mcnt, int Nn) {
  int n0 = blockIdx.x * NPB;
  int half = threadIdx.x >> 7;       // two nodes in flight per iteration
  int c = threadIdx.x & 127;
  float racc = 0.f; int rg = -1; int rlen = 0;
  for (int i = 0; i < NPB / 2; ++i) {
    int node = n0 + 2 * i + half;
    if (node >= Nn) break;
    float v = h[(size_t)node * HD + c];
    int g = gid[node], m = mid[node];
    atomicAdd(&msum[(size_t)m * HD + c], v);
    if (c == 0) atomicAdd(&mcnt[m], 1.f);
    if (g != rg) {                   // uniform branch within the 128-thread group
      if (rg >= 0) {
        atomicAdd(&gsum[(size_t)rg * HD + c], racc);
        if (c == 0) atomicAdd(&gcnt[rg], (float)rlen);
      }
      rg = g; racc = v; rlen = 1;
    } else { racc += v; rlen++; }
  }
  if (rg >= 0) {
    atomicAdd(&gsum[(size_t)rg * HD + c], racc);
    if (c == 0) atomicAdd(&gcnt[rg], (float)rlen);
  }
}

// ---------------- segment mean + fused layer-2 BN affine ----------------
// out = (sum/cnt)*scale + shift, scale = g*rsqrt(var+eps), shift = be - mu*scale.
// cnt==0 -> exact 0 row (matches reference empty-segment semantics).
template<bool WF32>
__global__ void seg_norm2(const float* __restrict__ sum, const float* __restrict__ cnt,
                          const float* __restrict__ colsum, const float* __restrict__ gamma,
                          const float* __restrict__ beta, float invM,
                          float* __restrict__ outf, unsigned short* __restrict__ outb, int R) {
  int idx = blockIdx.x * blockDim.x + threadIdx.x;
  if (idx >= R * HD) return;
  int r = idx >> 7, c = idx & 127;
  float n = cnt[r];
  float v = 0.f;
  if (n > 0.f) {
    float mu = colsum[c] * invM;
    float var = colsum[HD + c] * invM - mu * mu;
    float sc = gamma[c] * rsqrtf(var + 1e-5f);
    v = (sum[idx] / n) * sc + (beta[c] - mu * sc);
  }
  if constexpr (WF32) outf[idx] = v;
  outb[idx] = f2bf(v);
}

extern "C" void kernel_launch(void* const* d_in, const int* in_sizes, int n_in,
                              void* d_out, int out_size, void* d_ws, size_t ws_size,
                              hipStream_t stream) {
  const float* x0     = (const float*)d_in[0];
  const int*   src    = (const int*)d_in[1];
  const int*   dst    = (const int*)d_in[2];
  const int*   etype  = (const int*)d_in[3];
  const int*   gids   = (const int*)d_in[4];
  const int*   mids   = (const int*)d_in[5];
  const float* W1     = (const float*)d_in[6];
  const float* loopW1 = (const float*)d_in[7];
  const float* b1     = (const float*)d_in[8];
  const float* resW1  = (const float*)d_in[9];
  const float* resb1  = (const float*)d_in[10];
  const float* g1     = (const float*)d_in[11];
  const float* be1    = (const float*)d_in[12];
  const float* W2     = (const float*)d_in[13];
  const float* loopW2 = (const float*)d_in[14];
  const float* b2     = (const float*)d_in[15];
  const float* resW2  = (const float*)d_in[16];
  const float* resb2  = (const float*)d_in[17];
  const float* g2     = (const float*)d_in[18];
  const float* be2    = (const float*)d_in[19];
  const float* featW  = (const float*)d_in[20];   // [512,128]
  const float* featb  = (const float*)d_in[21];
  const float* mW1    = (const float*)d_in[22];   // [512,512]
  const float* mb1    = (const float*)d_in[23];
  const float* mW2    = (const float*)d_in[24];   // [256,512]
  const float* mb2    = (const float*)d_in[25];

  const int N = in_sizes[0] / HD;   // 30000
  const int E = in_sizes[1];        // 90000
  const int NG = 1500, NM = 6001, FFN = 512, OUT2 = 256;
  const int NCH = (E + 63) / 64 + NREL;
  const int NHD = N * HD;

  float* ws = (float*)d_ws;
  size_t off = 0;
  auto alloc = [&](size_t n) { float* p = ws + off; off += (n + 63) & ~((size_t)63); return p; };
  float* agg   = alloc(NHD);                 // f32 edge aggregate; later head intermediates
  float* hbuf  = alloc(NHD);                 // h1 f32 then h2 f32 (pre-BN)
  unsigned short* xb    = (unsigned short*)alloc(NHD / 2);  // x bf16, then h1 bf16
  unsigned short* W1tb  = (unsigned short*)alloc((size_t)NREL * HD * HD / 2);
  unsigned short* W2tb  = (unsigned short*)alloc((size_t)NREL * HD * HD / 2);
  unsigned short* lwT1b = (unsigned short*)alloc(HD * HD / 2);
  unsigned short* lwT2b = (unsigned short*)alloc(HD * HD / 2);
  unsigned short* rW1b  = (unsigned short*)alloc(HD * HD / 2);
  unsigned short* rW2b  = (unsigned short*)alloc(HD * HD / 2);
  unsigned short* featWb= (unsigned short*)alloc(FFN * HD / 2);
  unsigned short* mW1b  = (unsigned short*)alloc(FFN * FFN / 2);
  unsigned short* mW2b  = (unsigned short*)alloc(OUT2 * FFN / 2);
  float* colsum = alloc(2 * HD);
  float* gsum   = alloc((size_t)NG * HD);
  float* gcnt   = alloc(NG);
  float* msum   = alloc((size_t)NM * HD);
  float* mcnt   = alloc(NM);
  unsigned short* gfb  = (unsigned short*)alloc((size_t)NG * HD / 2);
  unsigned short* mbuf = (unsigned short*)alloc(((size_t)NM * HD + 63) / 2);
  int* counts    = (int*)alloc(NREL);
  int* offs      = (int*)alloc(NREL + 1);
  int* cursor    = (int*)alloc(NREL);
  int* chunk_rel = (int*)alloc(NCH);
  int* ssrc      = (int*)alloc((size_t)NCH * 64);
  int* sdst      = (int*)alloc((size_t)NCH * 64);
  // head intermediates alias agg (dead after layer-2 dual GEMM)
  unsigned short* fbuf_b = (unsigned short*)agg;             // <= 6000x512 bf16 = 6.1MB
  unsigned short* obuf_b = (unsigned short*)(agg + NHD / 2); // second half of agg

  float* out_gf = (float*)d_out;
  float* out_gl = out_gf + (size_t)NG * HD;
  float* out_sb = out_gl + (size_t)NG * OUT2;

  dim3 blk(256);

  // ---- one-time weight/feature casts ----
  cast_bf16<<<(NHD / 4 + 255) / 256, blk, 0, stream>>>(x0, xb, NHD / 4);
  transcast128<<<dim3(4, 4, NREL), blk, 0, stream>>>(W1, W1tb);
  transcast128<<<dim3(4, 4, NREL), blk, 0, stream>>>(W2, W2tb);
  transcast128<<<dim3(4, 4, 1), blk, 0, stream>>>(loopW1, lwT1b);
  transcast128<<<dim3(4, 4, 1), blk, 0, stream>>>(loopW2, lwT2b);
  cast_bf16<<<(HD * HD / 4 + 255) / 256, blk, 0, stream>>>(resW1, rW1b, HD * HD / 4);
  cast_bf16<<<(HD * HD / 4 + 255) / 256, blk, 0, stream>>>(resW2, rW2b, HD * HD / 4);
  cast_bf16<<<(FFN * HD / 4 + 255) / 256, blk, 0, stream>>>(featW, featWb, FFN * HD / 4);
  cast_bf16<<<(FFN * FFN / 4 + 255) / 256, blk, 0, stream>>>(mW1, mW1b, FFN * FFN / 4);
  cast_bf16<<<(OUT2 * FFN / 4 + 255) / 256, blk, 0, stream>>>(mW2, mW2b, OUT2 * FFN / 4);

  // ---- bucket edges by relation (once; reused by both layers) ----
  hipMemsetAsync(counts, 0, NREL * sizeof(int), stream);
  hipMemsetAsync(cursor, 0, NREL * sizeof(int), stream);
  hipMemsetAsync(chunk_rel, 0xFF, NCH * sizeof(int), stream);
  hipMemsetAsync(ssrc, 0xFF, (size_t)NCH * 64 * sizeof(int), stream);
  hipMemsetAsync(sdst, 0xFF, (size_t)NCH * 64 * sizeof(int), stream);
  edge_hist<<<(E + 255) / 256, blk, 0, stream>>>(etype, counts, E);
  rel_offsets<<<1, 128, 0, stream>>>(counts, offs);
  edge_scatter<<<(E + 255) / 256, blk, 0, stream>>>(src, dst, etype, offs, cursor,
                                                    ssrc, sdst, chunk_rel, E);

  dim3 gridDual(HD / 64, (N + 63) / 64);
  int bnBlocks = (N * (HD / 4) + 255) / 256;
  int egBlocks = (NCH + 1) / 2;

  // ---------------- layer 1 ----------------
  hipMemsetAsync(agg, 0, (size_t)NHD * sizeof(float), stream);
  hipMemsetAsync(colsum, 0, 2 * HD * sizeof(float), stream);
  edge_gemm_mfma<<<egBlocks, blk, 0, stream>>>(xb, W1tb, ssrc, sdst, chunk_rel, agg, NCH);
  gemm_mfma<true, 2, false><<<gridDual, blk, 0, stream>>>(
      xb, lwT1b, rW1b, b1, resb1, agg, hbuf, nullptr, colsum, N, HD, HD);
  bn_apply_bf16<<<bnBlocks, blk, 0, stream>>>(hbuf, xb, colsum, g1, be1, N);  // -> h1 bf16 (reuses xb)

  // ---------------- layer 2 (NO bn pass: BN folded into seg_norm2 affine) ----------------
  hipMemsetAsync(agg, 0, (size_t)NHD * sizeof(float), stream);
  hipMemsetAsync(colsum, 0, 2 * HD * sizeof(float), stream);
  edge_gemm_mfma<<<egBlocks, blk, 0, stream>>>(xb, W2tb, ssrc, sdst, chunk_rel, agg, NCH);
  gemm_mfma<true, 2, false><<<gridDual, blk, 0, stream>>>(
      xb, lwT2b, rW2b, b2, resb2, agg, hbuf, nullptr, colsum, N, HD, HD);  // hbuf = pre-BN h2

  // ---------------- readout ----------------
  hipMemsetAsync(gsum, 0, (size_t)NG * HD * sizeof(float), stream);
  hipMemsetAsync(gcnt, 0, NG * sizeof(float), stream);
  hipMemsetAsync(msum, 0, (size_t)NM * HD * sizeof(float), stream);
  hipMemsetAsync(mcnt, 0, NM * sizeof(float), stream);
  seg_accum2<<<(N + NPB - 1) / NPB, blk, 0, stream>>>(hbuf, gids, mids, gsum, gcnt, msum, mcnt, N);
  float invM = 1.f / (float)N;
  seg_norm2<true><<<(NG * HD + 255) / 256, blk, 0, stream>>>(
      gsum, gcnt, colsum, g2, be2, invM, out_gf, gfb, NG);
  seg_norm2<false><<<(NM * HD + 255) / 256, blk, 0, stream>>>(
      msum, mcnt, colsum, g2, be2, invM, nullptr, mbuf, NM);

  // head(g): f = g@featW^T + featb ; o = relu(f@mW1^T + mb1) ; out = o@mW2^T + mb2
  auto run_head = [&](const unsigned short* inb, int M, float* outp) {
    dim3 gA(FFN / 64, (M + 63) / 64);
    gemm_mfma<false, 0, true><<<gA, blk, 0, stream>>>(
        inb, featWb, nullptr, featb, nullptr, nullptr, nullptr, fbuf_b, nullptr, M, FFN, HD);
    dim3 gB(FFN / 64, (M + 63) / 64);
    gemm_mfma<false, 1, true><<<gB, blk, 0, stream>>>(
        fbuf_b, mW1b, nullptr, mb1, nullptr, nullptr, nullptr, obuf_b, nullptr, M, FFN, FFN);
    dim3 gC(OUT2 / 64, (M + 63) / 64);
    gemm_mfma<false, 0, false><<<gC, blk, 0, stream>>>(
        obuf_b, mW2b, nullptr, mb2, nullptr, nullptr, outp, nullptr, nullptr, M, OUT2, FFN);
  };
  run_head(gfb, NG, out_gl);
  run_head(mbuf + HD, NM - 1, out_sb);
}

// Round 7
// 303.977 us; speedup vs baseline: 4.4180x; 1.0015x over previous
//
#include <hip/hip_runtime.h>
#include <cstddef>

#define HD 128   // hidden dim
#define NREL 65
#define NPB 32   // nodes per block in seg_accum2

typedef __attribute__((ext_vector_type(8))) short bf16x8;   // 8 bf16 = 4 VGPRs (MFMA A/B frag)
typedef __attribute__((ext_vector_type(4))) float f32x4;    // MFMA C/D frag
#define MFMA_BF16(a, b, c) __builtin_amdgcn_mfma_f32_16x16x32_bf16(a, b, c, 0, 0, 0)

__device__ __forceinline__ unsigned short f2bf(float f) {   // RNE f32->bf16
  unsigned int u = __float_as_uint(f);
  u += 0x7FFFu + ((u >> 16) & 1u);
  return (unsigned short)(u >> 16);
}
__device__ __forceinline__ float reluf(float v) { return v > 0.f ? v : 0.f; }

// ---------------- f32 -> bf16 cast (vectorized, count % 4 == 0) ----------------
__global__ void cast_bf16(const float* __restrict__ in, unsigned short* __restrict__ out, int n4) {
  int i = blockIdx.x * blockDim.x + threadIdx.x;
  if (i >= n4) return;
  float4 v = ((const float4*)in)[i];
  ushort4 o;
  o.x = f2bf(v.x); o.y = f2bf(v.y); o.z = f2bf(v.z); o.w = f2bf(v.w);
  ((ushort4*)out)[i] = o;
}

// ---------------- 128x128 transpose + cast: out[n][k] = bf16(in[k][n]) ----------------
// grid (4, 4, R); block 256 (= 32x8)
__global__ void transcast128(const float* __restrict__ in, unsigned short* __restrict__ out) {
  __shared__ float t[32][33];
  size_t base = (size_t)blockIdx.z * HD * HD;
  int k0 = blockIdx.x * 32, n0 = blockIdx.y * 32;
  int tx = threadIdx.x & 31, ty = threadIdx.x >> 5;
#pragma unroll
  for (int it = 0; it < 4; ++it)
    t[ty + it * 8][tx] = in[base + (size_t)(k0 + ty + it * 8) * HD + n0 + tx];
  __syncthreads();
#pragma unroll
  for (int it = 0; it < 4; ++it)
    out[base + (size_t)(n0 + ty + it * 8) * HD + k0 + tx] = f2bf(t[tx][ty + it * 8]);
}

// ---------------- edge bucketing by relation (LDS-aggregated counting sort) ----------------
__global__ void edge_hist(const int* __restrict__ et, int* __restrict__ counts, int E) {
  __shared__ int lc[NREL];
  int tid = threadIdx.x;
  if (tid < NREL) lc[tid] = 0;
  __syncthreads();
  int i = blockIdx.x * blockDim.x + tid;
  if (i < E) atomicAdd(&lc[et[i]], 1);
  __syncthreads();
  if (tid < NREL && lc[tid] > 0) atomicAdd(&counts[tid], lc[tid]);
}

__global__ void rel_offsets(const int* __restrict__ counts, int* __restrict__ offs) {
  __shared__ int lc[NREL];
  int t = threadIdx.x;
  if (t < NREL) lc[t] = (counts[t] + 63) & ~63;
  __syncthreads();
  if (t <= NREL) {
    int o = 0;
    for (int r = 0; r < t; ++r) o += lc[r];
    offs[t] = o;
  }
}

__global__ void edge_scatter(const int* __restrict__ src, const int* __restrict__ dst,
                             const int* __restrict__ et, const int* __restrict__ offs,
                             int* __restrict__ cursor, int* __restrict__ ssrc,
                             int* __restrict__ sdst, int* __restrict__ chunk_rel, int E) {
  __shared__ int lc[NREL];
  __shared__ int lbase[NREL];
  int tid = threadIdx.x;
  if (tid < NREL) lc[tid] = 0;
  __syncthreads();
  int i = blockIdx.x * blockDim.x + tid;
  int r = -1, lrank = 0;
  if (i < E) { r = et[i]; lrank = atomicAdd(&lc[r], 1); }
  __syncthreads();
  if (tid < NREL && lc[tid] > 0) lbase[tid] = atomicAdd(&cursor[tid], lc[tid]);
  __syncthreads();
  if (i < E) {
    int slot = offs[r] + lbase[r] + lrank;
    ssrc[slot] = src[i];
    sdst[slot] = dst[i];
    chunk_rel[slot >> 6] = r;   // 64-aligned buckets: all writers of a chunk agree
  }
}

// ---------------- edge message GEMM (MFMA bf16): col-split, 1 chunk x half-W per block --------
// grid (NCH, 2): blockIdx.x = 64-edge chunk (single relation), blockIdx.y = 64-col half.
// Small LDS (17.4KB) + many blocks -> high occupancy to hide gather/atomic latency.
__global__ __launch_bounds__(256, 8) void edge_gemm_mfma(
    const unsigned short* __restrict__ xb, const unsigned short* __restrict__ Wt,
    const int* __restrict__ ssrc, const int* __restrict__ sdst,
    const int* __restrict__ chunk_rel, float* __restrict__ agg) {
  int chunk = blockIdx.x;
  int rel = chunk_rel[chunk];
  if (rel < 0) return;                        // pad chunk
  int half = blockIdx.y;

  __shared__ __align__(16) unsigned short Ws[64][136];  // 64 cols x 128 k, pad->2-way banks

  int tid = threadIdx.x;
  int lane = tid & 63, w = tid >> 6;
  int l15 = lane & 15, kg = lane >> 4;
  int base = chunk * 64;

  // issue edge-row gather address load first (longest latency chain)
  int srow = ssrc[base + w * 16 + l15];

  // stage this half's 64 rows of W^T[rel] (16KB), coalesced + conflict-free
  const unsigned short* Wr = Wt + (size_t)rel * HD * HD + (size_t)half * 64 * HD;
#pragma unroll
  for (int it = 0; it < 4; ++it) {
    int idx = it * 2048 + tid * 8;
    *(bf16x8*)&Ws[idx >> 7][idx & 127] = *(const bf16x8*)(Wr + idx);
  }

  // A frags in registers: wave w owns edges w*16..w*16+15; l15 = edge row, kg = k-group
  bf16x8 afr[4];
  const bf16x8 zb = {0, 0, 0, 0, 0, 0, 0, 0};
  if (srow >= 0) {
    const unsigned short* xr = xb + (size_t)srow * HD + kg * 8;
#pragma unroll
    for (int t = 0; t < 4; ++t) afr[t] = *(const bf16x8*)(xr + t * 32);
  } else {
#pragma unroll
    for (int t = 0; t < 4; ++t) afr[t] = zb;
  }
  __syncthreads();

  f32x4 acc[4];
  const f32x4 zf = {0.f, 0.f, 0.f, 0.f};
#pragma unroll
  for (int c = 0; c < 4; ++c) acc[c] = zf;
#pragma unroll
  for (int t = 0; t < 4; ++t)
#pragma unroll
    for (int c = 0; c < 4; ++c) {
      bf16x8 bfr = *(const bf16x8*)&Ws[c * 16 + l15][t * 32 + kg * 8];
      acc[c] = MFMA_BF16(afr[t], bfr, acc[c]);
    }

  // D: row(edge) = kg*4 + reg, col = half*64 + c*16 + l15 (16-lane coalesced atomics)
#pragma unroll
  for (int reg = 0; reg < 4; ++reg) {
    int d = sdst[base + w * 16 + kg * 4 + reg];
    if (d >= 0) {
      float* ap = agg + (size_t)d * HD + half * 64 + l15;
#pragma unroll
      for (int c = 0; c < 4; ++c) atomicAdd(ap + c * 16, acc[c][reg]);
    }
  }
}

// ---------------- generic NT GEMM (MFMA bf16): C = epi( A[M,K] @ B[N,K]^T ) ----------------
// 64x64 tile, 4 waves (2x2), each wave 32x32. EPI 0: +bias; 1: relu(+bias);
// 2 (DUAL): relu(acc1+b1+addend)+relu(acc2+b2), f32 C + BN colsum/colsumsq atomics.
template<bool DUAL, int EPI, bool OBF16>
__global__ __launch_bounds__(256) void gemm_mfma(
    const unsigned short* __restrict__ A, const unsigned short* __restrict__ B1,
    const unsigned short* __restrict__ B2, const float* __restrict__ bias1,
    const float* __restrict__ bias2, const float* __restrict__ addend,
    float* __restrict__ Cf, unsigned short* __restrict__ Cb,
    float* __restrict__ colsum, int M, int N, int K) {
  __shared__ __align__(16) unsigned short As[64][40];
  __shared__ __align__(16) unsigned short B1s[64][40];
  __shared__ __align__(16) unsigned short B2s[DUAL ? 64 : 1][40];
  __shared__ float cs[2][64];

  int tid = threadIdx.x;
  int lane = tid & 63, w = tid >> 6;
  int wr = w >> 1, wc = w & 1;
  int l15 = lane & 15, kg = lane >> 4;
  int row0 = blockIdx.y * 64, col0 = blockIdx.x * 64;
  int srow = tid >> 2, skc = (tid & 3) * 8;

  f32x4 acc1[2][2], acc2[2][2];
  const f32x4 zf = {0.f, 0.f, 0.f, 0.f};
  const bf16x8 zb = {0, 0, 0, 0, 0, 0, 0, 0};
#pragma unroll
  for (int i = 0; i < 2; ++i)
#pragma unroll
    for (int j = 0; j < 2; ++j) { acc1[i][j] = zf; acc2[i][j] = zf; }

  for (int k0 = 0; k0 < K; k0 += 32) {
    {
      int gr = row0 + srow;
      bf16x8 v = zb;
      if (gr < M) v = *(const bf16x8*)(A + (size_t)gr * K + k0 + skc);
      *(bf16x8*)&As[srow][skc] = v;
      *(bf16x8*)&B1s[srow][skc] = *(const bf16x8*)(B1 + (size_t)(col0 + srow) * K + k0 + skc);
      if constexpr (DUAL)
        *(bf16x8*)&B2s[srow][skc] = *(const bf16x8*)(B2 + (size_t)(col0 + srow) * K + k0 + skc);
    }
    __syncthreads();
    bf16x8 af[2], b1f[2];
#pragma unroll
    for (int i = 0; i < 2; ++i) af[i] = *(const bf16x8*)&As[wr * 32 + i * 16 + l15][kg * 8];
#pragma unroll
    for (int j = 0; j < 2; ++j) b1f[j] = *(const bf16x8*)&B1s[wc * 32 + j * 16 + l15][kg * 8];
#pragma unroll
    for (int i = 0; i < 2; ++i)
#pragma unroll
      for (int j = 0; j < 2; ++j) acc1[i][j] = MFMA_BF16(af[i], b1f[j], acc1[i][j]);
    if constexpr (DUAL) {
      bf16x8 b2f[2];
#pragma unroll
      for (int j = 0; j < 2; ++j) b2f[j] = *(const bf16x8*)&B2s[wc * 32 + j * 16 + l15][kg * 8];
#pragma unroll
      for (int i = 0; i < 2; ++i)
#pragma unroll
        for (int j = 0; j < 2; ++j) acc2[i][j] = MFMA_BF16(af[i], b2f[j], acc2[i][j]);
    }
    __syncthreads();
  }

  // epilogue. D: col = (wc*32 + j*16 + l15), row = (wr*32 + i*16 + kg*4 + reg)
  float s[2] = {0.f, 0.f}, sq[2] = {0.f, 0.f};
#pragma unroll
  for (int i = 0; i < 2; ++i)
#pragma unroll
    for (int reg = 0; reg < 4; ++reg) {
      int row = row0 + wr * 32 + i * 16 + kg * 4 + reg;
      if (row < M) {
#pragma unroll
        for (int j = 0; j < 2; ++j) {
          int col = col0 + wc * 32 + j * 16 + l15;
          float v = acc1[i][j][reg];
          if constexpr (EPI == 2) {
            v = reluf(v + bias1[col] + addend[(size_t)row * N + col])
              + reluf(acc2[i][j][reg] + bias2[col]);
            Cf[(size_t)row * N + col] = v;
            s[j] += v; sq[j] += v * v;
          } else {
            v += bias1[col];
            if constexpr (EPI == 1) v = reluf(v);
            if constexpr (OBF16) Cb[(size_t)row * N + col] = f2bf(v);
            else Cf[(size_t)row * N + col] = v;
          }
        }
      }
    }
  if constexpr (EPI == 2) {
    __syncthreads();
    if (tid < 128) ((float*)cs)[tid] = 0.f;
    __syncthreads();
#pragma unroll
    for (int j = 0; j < 2; ++j) {
      int lc = wc * 32 + j * 16 + l15;
      atomicAdd(&cs[0][lc], s[j]);
      atomicAdd(&cs[1][lc], sq[j]);
    }
    __syncthreads();
    if (tid < 64) {
      atomicAdd(&colsum[col0 + tid], cs[0][tid]);
      atomicAdd(&colsum[HD + col0 + tid], cs[1][tid]);
    }
  }
}

// ---------------- BatchNorm apply (layer 1 only: writes bf16 h for next layer) ----------------
__global__ void bn_apply_bf16(const float* __restrict__ h, unsigned short* __restrict__ hb,
                              const float* __restrict__ colsum, const float* __restrict__ gamma,
                              const float* __restrict__ beta, int M) {
  int i = blockIdx.x * blockDim.x + threadIdx.x;
  if (i >= M * (HD / 4)) return;
  int c0 = (i & 31) * 4;
  float invM = 1.f / (float)M;
  float4 v = ((const float4*)h)[i];
  float r[4] = {v.x, v.y, v.z, v.w};
#pragma unroll
  for (int j = 0; j < 4; ++j) {
    int c = c0 + j;
    float mu = colsum[c] * invM;
    float var = colsum[HD + c] * invM - mu * mu;
    r[j] = (r[j] - mu) * rsqrtf(var + 1e-5f) * gamma[c] + beta[c];
  }
  ushort4 o;
  o.x = f2bf(r[0]); o.y = f2bf(r[1]); o.z = f2bf(r[2]); o.w = f2bf(r[3]);
  ((ushort4*)hb)[i] = o;
}

// ---------------- segment-sum: sorted gids run-aggregated; motifs direct ----------------
// Reads PRE-BN h (layer-2 BN folded into seg_norm2 as per-column affine).
__global__ __launch_bounds__(256) void seg_accum2(
    const float* __restrict__ h, const int* __restrict__ gid, const int* __restrict__ mid,
    float* __restrict__ gsum, float* __restrict__ gcnt,
    float* __restrict__ msum, float* __restrict__ mcnt, int Nn) {
  int n0 = blockIdx.x * NPB;
  int half = threadIdx.x >> 7;       // two nodes in flight per iteration
  int c = threadIdx.x & 127;
  float racc = 0.f; int rg = -1; int rlen = 0;
  for (int i = 0; i < NPB / 2; ++i) {
    int node = n0 + 2 * i + half;
    if (node >= Nn) break;
    float v = h[(size_t)node * HD + c];
    int g = gid[node], m = mid[node];
    atomicAdd(&msum[(size_t)m * HD + c], v);
    if (c == 0) atomicAdd(&mcnt[m], 1.f);
    if (g != rg) {                   // uniform branch within the 128-thread group
      if (rg >= 0) {
        atomicAdd(&gsum[(size_t)rg * HD + c], racc);
        if (c == 0) atomicAdd(&gcnt[rg], (float)rlen);
      }
      rg = g; racc = v; rlen = 1;
    } else { racc += v; rlen++; }
  }
  if (rg >= 0) {
    atomicAdd(&gsum[(size_t)rg * HD + c], racc);
    if (c == 0) atomicAdd(&gcnt[rg], (float)rlen);
  }
}

// ---------------- segment mean + fused layer-2 BN affine ----------------
// out = (sum/cnt)*scale + shift, scale = g*rsqrt(var+eps), shift = be - mu*scale.
// cnt==0 -> exact 0 row (matches reference empty-segment semantics).
template<bool WF32>
__global__ void seg_norm2(const float* __restrict__ sum, const float* __restrict__ cnt,
                          const float* __restrict__ colsum, const float* __restrict__ gamma,
                          const float* __restrict__ beta, float invM,
                          float* __restrict__ outf, unsigned short* __restrict__ outb, int R) {
  int idx = blockIdx.x * blockDim.x + threadIdx.x;
  if (idx >= R * HD) return;
  int r = idx >> 7, c = idx & 127;
  float n = cnt[r];
  float v = 0.f;
  if (n > 0.f) {
    float mu = colsum[c] * invM;
    float var = colsum[HD + c] * invM - mu * mu;
    float sc = gamma[c] * rsqrtf(var + 1e-5f);
    v = (sum[idx] / n) * sc + (beta[c] - mu * sc);
  }
  if constexpr (WF32) outf[idx] = v;
  outb[idx] = f2bf(v);
}

extern "C" void kernel_launch(void* const* d_in, const int* in_sizes, int n_in,
                              void* d_out, int out_size, void* d_ws, size_t ws_size,
                              hipStream_t stream) {
  const float* x0     = (const float*)d_in[0];
  const int*   src    = (const int*)d_in[1];
  const int*   dst    = (const int*)d_in[2];
  const int*   etype  = (const int*)d_in[3];
  const int*   gids   = (const int*)d_in[4];
  const int*   mids   = (const int*)d_in[5];
  const float* W1     = (const float*)d_in[6];
  const float* loopW1 = (const float*)d_in[7];
  const float* b1     = (const float*)d_in[8];
  const float* resW1  = (const float*)d_in[9];
  const float* resb1  = (const float*)d_in[10];
  const float* g1     = (const float*)d_in[11];
  const float* be1    = (const float*)d_in[12];
  const float* W2     = (const float*)d_in[13];
  const float* loopW2 = (const float*)d_in[14];
  const float* b2     = (const float*)d_in[15];
  const float* resW2  = (const float*)d_in[16];
  const float* resb2  = (const float*)d_in[17];
  const float* g2     = (const float*)d_in[18];
  const float* be2    = (const float*)d_in[19];
  const float* featW  = (const float*)d_in[20];   // [512,128]
  const float* featb  = (const float*)d_in[21];
  const float* mW1    = (const float*)d_in[22];   // [512,512]
  const float* mb1    = (const float*)d_in[23];
  const float* mW2    = (const float*)d_in[24];   // [256,512]
  const float* mb2    = (const float*)d_in[25];

  const int N = in_sizes[0] / HD;   // 30000
  const int E = in_sizes[1];        // 90000
  const int NG = 1500, NM = 6001, FFN = 512, OUT2 = 256;
  const int NCH = (E + 63) / 64 + NREL;
  const int NHD = N * HD;

  float* ws = (float*)d_ws;
  size_t off = 0;
  auto alloc = [&](size_t n) { float* p = ws + off; off += (n + 63) & ~((size_t)63); return p; };
  float* agg   = alloc(NHD);                 // f32 edge aggregate; later head intermediates
  float* hbuf  = alloc(NHD);                 // h1 f32 then h2 f32 (pre-BN)
  unsigned short* xb    = (unsigned short*)alloc(NHD / 2);  // x bf16, then h1 bf16
  unsigned short* W1tb  = (unsigned short*)alloc((size_t)NREL * HD * HD / 2);
  unsigned short* W2tb  = (unsigned short*)alloc((size_t)NREL * HD * HD / 2);
  unsigned short* lwT1b = (unsigned short*)alloc(HD * HD / 2);
  unsigned short* lwT2b = (unsigned short*)alloc(HD * HD / 2);
  unsigned short* rW1b  = (unsigned short*)alloc(HD * HD / 2);
  unsigned short* rW2b  = (unsigned short*)alloc(HD * HD / 2);
  unsigned short* featWb= (unsigned short*)alloc(FFN * HD / 2);
  unsigned short* mW1b  = (unsigned short*)alloc(FFN * FFN / 2);
  unsigned short* mW2b  = (unsigned short*)alloc(OUT2 * FFN / 2);
  float* colsum = alloc(2 * HD);
  float* gsum   = alloc((size_t)NG * HD);
  float* gcnt   = alloc(NG);
  float* msum   = alloc((size_t)NM * HD);
  float* mcnt   = alloc(NM);
  unsigned short* gfb  = (unsigned short*)alloc((size_t)NG * HD / 2);
  unsigned short* mbuf = (unsigned short*)alloc(((size_t)NM * HD + 63) / 2);
  int* counts    = (int*)alloc(NREL);
  int* offs      = (int*)alloc(NREL + 1);
  int* cursor    = (int*)alloc(NREL);
  int* chunk_rel = (int*)alloc(NCH);
  int* ssrc      = (int*)alloc((size_t)NCH * 64);
  int* sdst      = (int*)alloc((size_t)NCH * 64);
  // head intermediates alias agg (dead after layer-2 dual GEMM)
  unsigned short* fbuf_b = (unsigned short*)agg;             // <= 6000x512 bf16 = 6.1MB
  unsigned short* obuf_b = (unsigned short*)(agg + NHD / 2); // second half of agg

  float* out_gf = (float*)d_out;
  float* out_gl = out_gf + (size_t)NG * HD;
  float* out_sb = out_gl + (size_t)NG * OUT2;

  dim3 blk(256);

  // ---- one-time weight/feature casts ----
  cast_bf16<<<(NHD / 4 + 255) / 256, blk, 0, stream>>>(x0, xb, NHD / 4);
  transcast128<<<dim3(4, 4, NREL), blk, 0, stream>>>(W1, W1tb);
  transcast128<<<dim3(4, 4, NREL), blk, 0, stream>>>(W2, W2tb);
  transcast128<<<dim3(4, 4, 1), blk, 0, stream>>>(loopW1, lwT1b);
  transcast128<<<dim3(4, 4, 1), blk, 0, stream>>>(loopW2, lwT2b);
  cast_bf16<<<(HD * HD / 4 + 255) / 256, blk, 0, stream>>>(resW1, rW1b, HD * HD / 4);
  cast_bf16<<<(HD * HD / 4 + 255) / 256, blk, 0, stream>>>(resW2, rW2b, HD * HD / 4);
  cast_bf16<<<(FFN * HD / 4 + 255) / 256, blk, 0, stream>>>(featW, featWb, FFN * HD / 4);
  cast_bf16<<<(FFN * FFN / 4 + 255) / 256, blk, 0, stream>>>(mW1, mW1b, FFN * FFN / 4);
  cast_bf16<<<(OUT2 * FFN / 4 + 255) / 256, blk, 0, stream>>>(mW2, mW2b, OUT2 * FFN / 4);

  // ---- bucket edges by relation (once; reused by both layers) ----
  hipMemsetAsync(counts, 0, NREL * sizeof(int), stream);
  hipMemsetAsync(cursor, 0, NREL * sizeof(int), stream);
  hipMemsetAsync(chunk_rel, 0xFF, NCH * sizeof(int), stream);
  hipMemsetAsync(ssrc, 0xFF, (size_t)NCH * 64 * sizeof(int), stream);
  hipMemsetAsync(sdst, 0xFF, (size_t)NCH * 64 * sizeof(int), stream);
  edge_hist<<<(E + 255) / 256, blk, 0, stream>>>(etype, counts, E);
  rel_offsets<<<1, 128, 0, stream>>>(counts, offs);
  edge_scatter<<<(E + 255) / 256, blk, 0, stream>>>(src, dst, etype, offs, cursor,
                                                    ssrc, sdst, chunk_rel, E);

  dim3 gridDual(HD / 64, (N + 63) / 64);
  dim3 gridEdge(NCH, 2);
  int bnBlocks = (N * (HD / 4) + 255) / 256;

  // ---------------- layer 1 ----------------
  hipMemsetAsync(agg, 0, (size_t)NHD * sizeof(float), stream);
  hipMemsetAsync(colsum, 0, 2 * HD * sizeof(float), stream);
  edge_gemm_mfma<<<gridEdge, blk, 0, stream>>>(xb, W1tb, ssrc, sdst, chunk_rel, agg);
  gemm_mfma<true, 2, false><<<gridDual, blk, 0, stream>>>(
      xb, lwT1b, rW1b, b1, resb1, agg, hbuf, nullptr, colsum, N, HD, HD);
  bn_apply_bf16<<<bnBlocks, blk, 0, stream>>>(hbuf, xb, colsum, g1, be1, N);  // -> h1 bf16 (reuses xb)

  // ---------------- layer 2 (NO bn pass: BN folded into seg_norm2 affine) ----------------
  hipMemsetAsync(agg, 0, (size_t)NHD * sizeof(float), stream);
  hipMemsetAsync(colsum, 0, 2 * HD * sizeof(float), stream);
  edge_gemm_mfma<<<gridEdge, blk, 0, stream>>>(xb, W2tb, ssrc, sdst, chunk_rel, agg);
  gemm_mfma<true, 2, false><<<gridDual, blk, 0, stream>>>(
      xb, lwT2b, rW2b, b2, resb2, agg, hbuf, nullptr, colsum, N, HD, HD);  // hbuf = pre-BN h2

  // ---------------- readout ----------------
  hipMemsetAsync(gsum, 0, (size_t)NG * HD * sizeof(float), stream);
  hipMemsetAsync(gcnt, 0, NG * sizeof(float), stream);
  hipMemsetAsync(msum, 0, (size_t)NM * HD * sizeof(float), stream);
  hipMemsetAsync(mcnt, 0, NM * sizeof(float), stream);
  seg_accum2<<<(N + NPB - 1) / NPB, blk, 0, stream>>>(hbuf, gids, mids, gsum, gcnt, msum, mcnt, N);
  float invM = 1.f / (float)N;
  seg_norm2<true><<<(NG * HD + 255) / 256, blk, 0, stream>>>(
      gsum, gcnt, colsum, g2, be2, invM, out_gf, gfb, NG);
  seg_norm2<false><<<(NM * HD + 255) / 256, blk, 0, stream>>>(
      msum, mcnt, colsum, g2, be2, invM, nullptr, mbuf, NM);

  // head(g): f = g@featW^T + featb ; o = relu(f@mW1^T + mb1) ; out = o@mW2^T + mb2
  auto run_head = [&](const unsigned short* inb, int M, float* outp) {
    dim3 gA(FFN / 64, (M + 63) / 64);
    gemm_mfma<false, 0, true><<<gA, blk, 0, stream>>>(
        inb, featWb, nullptr, featb, nullptr, nullptr, nullptr, fbuf_b, nullptr, M, FFN, HD);
    dim3 gB(FFN / 64, (M + 63) / 64);
    gemm_mfma<false, 1, true><<<gB, blk, 0, stream>>>(
        fbuf_b, mW1b, nullptr, mb1, nullptr, nullptr, nullptr, obuf_b, nullptr, M, FFN, FFN);
    dim3 gC(OUT2 / 64, (M + 63) / 64);
    gemm_mfma<false, 0, false><<<gC, blk, 0, stream>>>(
        obuf_b, mW2b, nullptr, mb2, nullptr, nullptr, outp, nullptr, nullptr, M, OUT2, FFN);
  };
  run_head(gfb, NG, out_gl);
  run_head(mbuf + HD, NM - 1, out_sb);
}

// Round 8
// 245.786 us; speedup vs baseline: 5.4639x; 1.2368x over previous
//
#include <hip/hip_runtime.h>
#include <cstddef>

#define HD 128   // hidden dim
#define NREL 65
#define NPB 32   // nodes per block in seg_accum2

typedef __attribute__((ext_vector_type(8))) short bf16x8;   // 8 bf16 = 4 VGPRs (MFMA A/B frag)
typedef __attribute__((ext_vector_type(4))) float f32x4;    // MFMA C/D frag
#define MFMA_BF16(a, b, c) __builtin_amdgcn_mfma_f32_16x16x32_bf16(a, b, c, 0, 0, 0)

__device__ __forceinline__ unsigned short f2bf(float f) {   // RNE f32->bf16
  unsigned int u = __float_as_uint(f);
  u += 0x7FFFu + ((u >> 16) & 1u);
  return (unsigned short)(u >> 16);
}
__device__ __forceinline__ float reluf(float v) { return v > 0.f ? v : 0.f; }

// ---------------- fused multi-segment f32 -> bf16 cast ----------------
struct CastSegs {
  const float* src[6];
  unsigned short* dst[6];
  int n4[6];     // float4 quads per segment
};
__global__ void cast_bf16_multi(CastSegs segs, int total4) {
  int i = blockIdx.x * blockDim.x + threadIdx.x;
  if (i >= total4) return;
  int base = 0, s = -1, j = 0;
#pragma unroll
  for (int k = 0; k < 6; ++k) {
    if (s < 0 && i < base + segs.n4[k]) { s = k; j = i - base; }
    base += segs.n4[k];
  }
  float4 v = ((const float4*)segs.src[s])[j];
  ushort4 o;
  o.x = f2bf(v.x); o.y = f2bf(v.y); o.z = f2bf(v.z); o.w = f2bf(v.w);
  ((ushort4*)segs.dst[s])[j] = o;
}

// ---------------- fused 128x128 transpose+cast for W1|W2|loopW1|loopW2 ----------------
// grid (4, 4, 2*NREL+2); block 256 (= 32x8): out[n][k] = bf16(in[k][n])
__global__ void transcast_all(const float* __restrict__ W1, const float* __restrict__ W2,
                              const float* __restrict__ lw1, const float* __restrict__ lw2,
                              unsigned short* __restrict__ W1t, unsigned short* __restrict__ W2t,
                              unsigned short* __restrict__ l1t, unsigned short* __restrict__ l2t) {
  __shared__ float t[32][33];
  int z = blockIdx.z;
  const float* in; unsigned short* out;
  if (z < NREL)            { in = W1 + (size_t)z * HD * HD;          out = W1t + (size_t)z * HD * HD; }
  else if (z < 2 * NREL)   { in = W2 + (size_t)(z - NREL) * HD * HD; out = W2t + (size_t)(z - NREL) * HD * HD; }
  else if (z == 2 * NREL)  { in = lw1; out = l1t; }
  else                     { in = lw2; out = l2t; }
  int k0 = blockIdx.x * 32, n0 = blockIdx.y * 32;
  int tx = threadIdx.x & 31, ty = threadIdx.x >> 5;
#pragma unroll
  for (int it = 0; it < 4; ++it)
    t[ty + it * 8][tx] = in[(size_t)(k0 + ty + it * 8) * HD + n0 + tx];
  __syncthreads();
#pragma unroll
  for (int it = 0; it < 4; ++it)
    out[(size_t)(n0 + ty + it * 8) * HD + k0 + tx] = f2bf(t[tx][ty + it * 8]);
}

// ---------------- edge bucketing by relation (LDS-aggregated counting sort) ----------------
__global__ void edge_hist(const int* __restrict__ et, int* __restrict__ counts, int E) {
  __shared__ int lc[NREL];
  int tid = threadIdx.x;
  if (tid < NREL) lc[tid] = 0;
  __syncthreads();
  int i = blockIdx.x * blockDim.x + tid;
  if (i < E) atomicAdd(&lc[et[i]], 1);
  __syncthreads();
  if (tid < NREL && lc[tid] > 0) atomicAdd(&counts[tid], lc[tid]);
}

__global__ void rel_offsets(const int* __restrict__ counts, int* __restrict__ offs) {
  __shared__ int lc[NREL];
  int t = threadIdx.x;
  if (t < NREL) lc[t] = (counts[t] + 63) & ~63;
  __syncthreads();
  if (t <= NREL) {
    int o = 0;
    for (int r = 0; r < t; ++r) o += lc[r];
    offs[t] = o;
  }
}

__global__ void edge_scatter(const int* __restrict__ src, const int* __restrict__ dst,
                             const int* __restrict__ et, const int* __restrict__ offs,
                             int* __restrict__ cursor, int* __restrict__ ssrc,
                             int* __restrict__ sdst, int* __restrict__ chunk_rel, int E) {
  __shared__ int lc[NREL];
  __shared__ int lbase[NREL];
  int tid = threadIdx.x;
  if (tid < NREL) lc[tid] = 0;
  __syncthreads();
  int i = blockIdx.x * blockDim.x + tid;
  int r = -1, lrank = 0;
  if (i < E) { r = et[i]; lrank = atomicAdd(&lc[r], 1); }
  __syncthreads();
  if (tid < NREL && lc[tid] > 0) lbase[tid] = atomicAdd(&cursor[tid], lc[tid]);
  __syncthreads();
  if (i < E) {
    int slot = offs[r] + lbase[r] + lrank;
    ssrc[slot] = src[i];
    sdst[slot] = dst[i];
    chunk_rel[slot >> 6] = r;   // 64-aligned buckets: all writers of a chunk agree
  }
}

// ---------------- edge message GEMM (MFMA bf16): col-split, 1 chunk x half-W per block --------
// grid (NCH, 2): blockIdx.x = 64-edge chunk (single relation), blockIdx.y = 64-col half.
__global__ __launch_bounds__(256, 8) void edge_gemm_mfma(
    const unsigned short* __restrict__ xb, const unsigned short* __restrict__ Wt,
    const int* __restrict__ ssrc, const int* __restrict__ sdst,
    const int* __restrict__ chunk_rel, float* __restrict__ agg) {
  int chunk = blockIdx.x;
  int rel = chunk_rel[chunk];
  if (rel < 0) return;                        // pad chunk
  int half = blockIdx.y;

  __shared__ __align__(16) unsigned short Ws[64][136];  // 64 cols x 128 k, pad->2-way banks

  int tid = threadIdx.x;
  int lane = tid & 63, w = tid >> 6;
  int l15 = lane & 15, kg = lane >> 4;
  int base = chunk * 64;

  // issue gather-index loads first (longest latency chains)
  int srow = ssrc[base + w * 16 + l15];
  int drow[4];
#pragma unroll
  for (int reg = 0; reg < 4; ++reg) drow[reg] = sdst[base + w * 16 + kg * 4 + reg];

  // stage this half's 64 rows of W^T[rel] (16KB), coalesced + conflict-free
  const unsigned short* Wr = Wt + (size_t)rel * HD * HD + (size_t)half * 64 * HD;
#pragma unroll
  for (int it = 0; it < 4; ++it) {
    int idx = it * 2048 + tid * 8;
    *(bf16x8*)&Ws[idx >> 7][idx & 127] = *(const bf16x8*)(Wr + idx);
  }

  // A frags: wave w owns edges w*16..w*16+15; l15 = edge row, kg = k-group
  bf16x8 afr[4];
  const bf16x8 zb = {0, 0, 0, 0, 0, 0, 0, 0};
  if (srow >= 0) {
    const unsigned short* xr = xb + (size_t)srow * HD + kg * 8;
#pragma unroll
    for (int t = 0; t < 4; ++t) afr[t] = *(const bf16x8*)(xr + t * 32);
  } else {
#pragma unroll
    for (int t = 0; t < 4; ++t) afr[t] = zb;
  }
  __syncthreads();

  f32x4 acc[4];
  const f32x4 zf = {0.f, 0.f, 0.f, 0.f};
#pragma unroll
  for (int c = 0; c < 4; ++c) acc[c] = zf;
#pragma unroll
  for (int t = 0; t < 4; ++t)
#pragma unroll
    for (int c = 0; c < 4; ++c) {
      bf16x8 bfr = *(const bf16x8*)&Ws[c * 16 + l15][t * 32 + kg * 8];
      acc[c] = MFMA_BF16(afr[t], bfr, acc[c]);
    }

  // D: row(edge) = kg*4 + reg, col = half*64 + c*16 + l15 (16-lane coalesced atomics)
#pragma unroll
  for (int reg = 0; reg < 4; ++reg) {
    int d = drow[reg];
    if (d >= 0) {
      float* ap = agg + (size_t)d * HD + half * 64 + l15;
#pragma unroll
      for (int c = 0; c < 4; ++c) atomicAdd(ap + c * 16, acc[c][reg]);
    }
  }
}

// ---------------- generic NT GEMM (MFMA bf16): C = epi( A[M,K] @ B[N,K]^T ) ----------------
template<bool DUAL, int EPI, bool OBF16>
__global__ __launch_bounds__(256) void gemm_mfma(
    const unsigned short* __restrict__ A, const unsigned short* __restrict__ B1,
    const unsigned short* __restrict__ B2, const float* __restrict__ bias1,
    const float* __restrict__ bias2, const float* __restrict__ addend,
    float* __restrict__ Cf, unsigned short* __restrict__ Cb,
    float* __restrict__ colsum, int M, int N, int K) {
  __shared__ __align__(16) unsigned short As[64][40];
  __shared__ __align__(16) unsigned short B1s[64][40];
  __shared__ __align__(16) unsigned short B2s[DUAL ? 64 : 1][40];
  __shared__ float cs[2][64];

  int tid = threadIdx.x;
  int lane = tid & 63, w = tid >> 6;
  int wr = w >> 1, wc = w & 1;
  int l15 = lane & 15, kg = lane >> 4;
  int row0 = blockIdx.y * 64, col0 = blockIdx.x * 64;
  int srow = tid >> 2, skc = (tid & 3) * 8;

  f32x4 acc1[2][2], acc2[2][2];
  const f32x4 zf = {0.f, 0.f, 0.f, 0.f};
  const bf16x8 zb = {0, 0, 0, 0, 0, 0, 0, 0};
#pragma unroll
  for (int i = 0; i < 2; ++i)
#pragma unroll
    for (int j = 0; j < 2; ++j) { acc1[i][j] = zf; acc2[i][j] = zf; }

  for (int k0 = 0; k0 < K; k0 += 32) {
    {
      int gr = row0 + srow;
      bf16x8 v = zb;
      if (gr < M) v = *(const bf16x8*)(A + (size_t)gr * K + k0 + skc);
      *(bf16x8*)&As[srow][skc] = v;
      *(bf16x8*)&B1s[srow][skc] = *(const bf16x8*)(B1 + (size_t)(col0 + srow) * K + k0 + skc);
      if constexpr (DUAL)
        *(bf16x8*)&B2s[srow][skc] = *(const bf16x8*)(B2 + (size_t)(col0 + srow) * K + k0 + skc);
    }
    __syncthreads();
    bf16x8 af[2], b1f[2];
#pragma unroll
    for (int i = 0; i < 2; ++i) af[i] = *(const bf16x8*)&As[wr * 32 + i * 16 + l15][kg * 8];
#pragma unroll
    for (int j = 0; j < 2; ++j) b1f[j] = *(const bf16x8*)&B1s[wc * 32 + j * 16 + l15][kg * 8];
#pragma unroll
    for (int i = 0; i < 2; ++i)
#pragma unroll
      for (int j = 0; j < 2; ++j) acc1[i][j] = MFMA_BF16(af[i], b1f[j], acc1[i][j]);
    if constexpr (DUAL) {
      bf16x8 b2f[2];
#pragma unroll
      for (int j = 0; j < 2; ++j) b2f[j] = *(const bf16x8*)&B2s[wc * 32 + j * 16 + l15][kg * 8];
#pragma unroll
      for (int i = 0; i < 2; ++i)
#pragma unroll
        for (int j = 0; j < 2; ++j) acc2[i][j] = MFMA_BF16(af[i], b2f[j], acc2[i][j]);
    }
    __syncthreads();
  }

  // epilogue. D: col = (wc*32 + j*16 + l15), row = (wr*32 + i*16 + kg*4 + reg)
  float s[2] = {0.f, 0.f}, sq[2] = {0.f, 0.f};
#pragma unroll
  for (int i = 0; i < 2; ++i)
#pragma unroll
    for (int reg = 0; reg < 4; ++reg) {
      int row = row0 + wr * 32 + i * 16 + kg * 4 + reg;
      if (row < M) {
#pragma unroll
        for (int j = 0; j < 2; ++j) {
          int col = col0 + wc * 32 + j * 16 + l15;
          float v = acc1[i][j][reg];
          if constexpr (EPI == 2) {
            v = reluf(v + bias1[col] + addend[(size_t)row * N + col])
              + reluf(acc2[i][j][reg] + bias2[col]);
            Cf[(size_t)row * N + col] = v;
            s[j] += v; sq[j] += v * v;
          } else {
            v += bias1[col];
            if constexpr (EPI == 1) v = reluf(v);
            if constexpr (OBF16) Cb[(size_t)row * N + col] = f2bf(v);
            else Cf[(size_t)row * N + col] = v;
          }
        }
      }
    }
  if constexpr (EPI == 2) {
    __syncthreads();
    if (tid < 128) ((float*)cs)[tid] = 0.f;
    __syncthreads();
#pragma unroll
    for (int j = 0; j < 2; ++j) {
      int lc = wc * 32 + j * 16 + l15;
      atomicAdd(&cs[0][lc], s[j]);
      atomicAdd(&cs[1][lc], sq[j]);
    }
    __syncthreads();
    if (tid < 64) {
      atomicAdd(&colsum[col0 + tid], cs[0][tid]);
      atomicAdd(&colsum[HD + col0 + tid], cs[1][tid]);
    }
  }
}

// ---------------- BatchNorm apply (layer 1 only: writes bf16 h for next layer) ----------------
__global__ void bn_apply_bf16(const float* __restrict__ h, unsigned short* __restrict__ hb,
                              const float* __restrict__ colsum, const float* __restrict__ gamma,
                              const float* __restrict__ beta, int M) {
  int i = blockIdx.x * blockDim.x + threadIdx.x;
  if (i >= M * (HD / 4)) return;
  int c0 = (i & 31) * 4;
  float invM = 1.f / (float)M;
  float4 v = ((const float4*)h)[i];
  float r[4] = {v.x, v.y, v.z, v.w};
#pragma unroll
  for (int j = 0; j < 4; ++j) {
    int c = c0 + j;
    float mu = colsum[c] * invM;
    float var = colsum[HD + c] * invM - mu * mu;
    r[j] = (r[j] - mu) * rsqrtf(var + 1e-5f) * gamma[c] + beta[c];
  }
  ushort4 o;
  o.x = f2bf(r[0]); o.y = f2bf(r[1]); o.z = f2bf(r[2]); o.w = f2bf(r[3]);
  ((ushort4*)hb)[i] = o;
}

// ---------------- segment-sum: sorted gids run-aggregated; motifs direct ----------------
__global__ __launch_bounds__(256) void seg_accum2(
    const float* __restrict__ h, const int* __restrict__ gid, const int* __restrict__ mid,
    float* __restrict__ gsum, float* __restrict__ gcnt,
    float* __restrict__ msum, float* __restrict__ mcnt, int Nn) {
  int n0 = blockIdx.x * NPB;
  int half = threadIdx.x >> 7;
  int c = threadIdx.x & 127;
  float racc = 0.f; int rg = -1; int rlen = 0;
  for (int i = 0; i < NPB / 2; ++i) {
    int node = n0 + 2 * i + half;
    if (node >= Nn) break;
    float v = h[(size_t)node * HD + c];
    int g = gid[node], m = mid[node];
    atomicAdd(&msum[(size_t)m * HD + c], v);
    if (c == 0) atomicAdd(&mcnt[m], 1.f);
    if (g != rg) {
      if (rg >= 0) {
        atomicAdd(&gsum[(size_t)rg * HD + c], racc);
        if (c == 0) atomicAdd(&gcnt[rg], (float)rlen);
      }
      rg = g; racc = v; rlen = 1;
    } else { racc += v; rlen++; }
  }
  if (rg >= 0) {
    atomicAdd(&gsum[(size_t)rg * HD + c], racc);
    if (c == 0) atomicAdd(&gcnt[rg], (float)rlen);
  }
}

// ---------------- unified segment mean + fused layer-2 BN affine ----------------
// rows [0,NG): graphs -> out_gf (f32) + headin rows [0,NG)
// rows [NG,NG+NM): motifs -> headin rows [NG + r'-1] for r' in [1,NM) (row 0 dropped)
__global__ void seg_norm_all(const float* __restrict__ gsum, const float* __restrict__ gcnt,
                             const float* __restrict__ msum, const float* __restrict__ mcnt,
                             const float* __restrict__ colsum, const float* __restrict__ gamma,
                             const float* __restrict__ beta, float invM,
                             float* __restrict__ out_gf, unsigned short* __restrict__ headin,
                             int NGr, int NMr) {
  int idx = blockIdx.x * blockDim.x + threadIdx.x;
  if (idx >= (NGr + NMr) * HD) return;
  int r = idx >> 7, c = idx & 127;
  float n, sum;
  if (r < NGr) { n = gcnt[r]; sum = gsum[idx]; }
  else         { n = mcnt[r - NGr]; sum = msum[idx - NGr * HD]; }
  float v = 0.f;
  if (n > 0.f) {
    float mu = colsum[c] * invM;
    float var = colsum[HD + c] * invM - mu * mu;
    float sc = gamma[c] * rsqrtf(var + 1e-5f);
    v = (sum / n) * sc + (beta[c] - mu * sc);
  }
  if (r < NGr) {
    out_gf[idx] = v;
    headin[idx] = f2bf(v);
  } else {
    int rm = r - NGr;
    if (rm > 0) headin[(size_t)(NGr + rm - 1) * HD + c] = f2bf(v);
  }
}

extern "C" void kernel_launch(void* const* d_in, const int* in_sizes, int n_in,
                              void* d_out, int out_size, void* d_ws, size_t ws_size,
                              hipStream_t stream) {
  const float* x0     = (const float*)d_in[0];
  const int*   src    = (const int*)d_in[1];
  const int*   dst    = (const int*)d_in[2];
  const int*   etype  = (const int*)d_in[3];
  const int*   gids   = (const int*)d_in[4];
  const int*   mids   = (const int*)d_in[5];
  const float* W1     = (const float*)d_in[6];
  const float* loopW1 = (const float*)d_in[7];
  const float* b1     = (const float*)d_in[8];
  const float* resW1  = (const float*)d_in[9];
  const float* resb1  = (const float*)d_in[10];
  const float* g1     = (const float*)d_in[11];
  const float* be1    = (const float*)d_in[12];
  const float* W2     = (const float*)d_in[13];
  const float* loopW2 = (const float*)d_in[14];
  const float* b2     = (const float*)d_in[15];
  const float* resW2  = (const float*)d_in[16];
  const float* resb2  = (const float*)d_in[17];
  const float* g2     = (const float*)d_in[18];
  const float* be2    = (const float*)d_in[19];
  const float* featW  = (const float*)d_in[20];   // [512,128]
  const float* featb  = (const float*)d_in[21];
  const float* mW1    = (const float*)d_in[22];   // [512,512]
  const float* mb1    = (const float*)d_in[23];
  const float* mW2    = (const float*)d_in[24];   // [256,512]
  const float* mb2    = (const float*)d_in[25];

  const int N = in_sizes[0] / HD;   // 30000
  const int E = in_sizes[1];        // 90000
  const int NG = 1500, NM = 6001, FFN = 512, OUT2 = 256;
  const int NCH = (E + 63) / 64 + NREL;
  const int NHD = N * HD;
  const int NHEAD = NG + NM - 1;    // 7500 unified head rows

  float* ws = (float*)d_ws;
  size_t off = 0;
  auto alloc = [&](size_t n) { float* p = ws + off; off += (n + 63) & ~((size_t)63); return p; };
  // agg + colsum contiguous (fused memset)
  float* agg    = alloc(NHD);
  float* colsum = alloc(2 * HD);
  float* hbuf   = alloc(NHD);
  unsigned short* xb    = (unsigned short*)alloc(NHD / 2);
  unsigned short* W1tb  = (unsigned short*)alloc((size_t)NREL * HD * HD / 2);
  unsigned short* W2tb  = (unsigned short*)alloc((size_t)NREL * HD * HD / 2);
  unsigned short* lwT1b = (unsigned short*)alloc(HD * HD / 2);
  unsigned short* lwT2b = (unsigned short*)alloc(HD * HD / 2);
  unsigned short* rW1b  = (unsigned short*)alloc(HD * HD / 2);
  unsigned short* rW2b  = (unsigned short*)alloc(HD * HD / 2);
  unsigned short* featWb= (unsigned short*)alloc(FFN * HD / 2);
  unsigned short* mW1b  = (unsigned short*)alloc(FFN * FFN / 2);
  unsigned short* mW2b  = (unsigned short*)alloc(OUT2 * FFN / 2);
  // readout span contiguous (fused memset): gsum, gcnt, msum, mcnt
  float* gsum   = alloc((size_t)NG * HD);
  float* gcnt   = alloc(NG);
  float* msum   = alloc((size_t)NM * HD);
  float* mcnt   = alloc(NM);
  size_t readout_end = off;
  unsigned short* headin = (unsigned short*)alloc((size_t)NHEAD * HD / 2);
  // counts + cursor contiguous (fused memset)
  int* counts    = (int*)alloc(NREL);
  int* cursor    = (int*)alloc(NREL);
  int* offs      = (int*)alloc(NREL + 1);
  // sort span contiguous (fused 0xFF memset): chunk_rel, ssrc, sdst
  int* chunk_rel = (int*)alloc(NCH);
  int* ssrc      = (int*)alloc((size_t)NCH * 64);
  int* sdst      = (int*)alloc((size_t)NCH * 64);
  size_t sort_end = off;
  // head intermediates alias agg (dead after layer-2 dual GEMM): 2 x 7500x512 bf16 = 15.4MB
  unsigned short* fbuf_b = (unsigned short*)agg;
  unsigned short* obuf_b = (unsigned short*)(agg + NHD / 2);

  float* out_gf = (float*)d_out;
  float* out_gl = out_gf + (size_t)NG * HD;       // 7500x256 contiguous (global then sub)

  dim3 blk(256);

  // ---- one-time casts: 2 dispatches ----
  CastSegs cs{};
  cs.src[0] = x0;    cs.dst[0] = xb;     cs.n4[0] = NHD / 4;
  cs.src[1] = resW1; cs.dst[1] = rW1b;   cs.n4[1] = HD * HD / 4;
  cs.src[2] = resW2; cs.dst[2] = rW2b;   cs.n4[2] = HD * HD / 4;
  cs.src[3] = featW; cs.dst[3] = featWb; cs.n4[3] = FFN * HD / 4;
  cs.src[4] = mW1;   cs.dst[4] = mW1b;   cs.n4[4] = FFN * FFN / 4;
  cs.src[5] = mW2;   cs.dst[5] = mW2b;   cs.n4[5] = OUT2 * FFN / 4;
  int total4 = cs.n4[0] + cs.n4[1] + cs.n4[2] + cs.n4[3] + cs.n4[4] + cs.n4[5];
  cast_bf16_multi<<<(total4 + 255) / 256, blk, 0, stream>>>(cs, total4);
  transcast_all<<<dim3(4, 4, 2 * NREL + 2), blk, 0, stream>>>(
      W1, W2, loopW1, loopW2, W1tb, W2tb, lwT1b, lwT2b);

  // ---- bucket edges by relation (once; reused by both layers) ----
  hipMemsetAsync(counts, 0, 2 * 128 * sizeof(int), stream);                       // counts+cursor
  hipMemsetAsync(chunk_rel, 0xFF, (sort_end - (size_t)((float*)chunk_rel - ws)) * sizeof(float), stream);
  edge_hist<<<(E + 255) / 256, blk, 0, stream>>>(etype, counts, E);
  rel_offsets<<<1, 128, 0, stream>>>(counts, offs);
  edge_scatter<<<(E + 255) / 256, blk, 0, stream>>>(src, dst, etype, offs, cursor,
                                                    ssrc, sdst, chunk_rel, E);

  dim3 gridDual(HD / 64, (N + 63) / 64);
  dim3 gridEdge(NCH, 2);
  int bnBlocks = (N * (HD / 4) + 255) / 256;
  size_t aggSpan = (NHD + 2 * HD + 64) * sizeof(float);   // agg + colsum

  // ---------------- layer 1 ----------------
  hipMemsetAsync(agg, 0, aggSpan, stream);
  edge_gemm_mfma<<<gridEdge, blk, 0, stream>>>(xb, W1tb, ssrc, sdst, chunk_rel, agg);
  gemm_mfma<true, 2, false><<<gridDual, blk, 0, stream>>>(
      xb, lwT1b, rW1b, b1, resb1, agg, hbuf, nullptr, colsum, N, HD, HD);
  bn_apply_bf16<<<bnBlocks, blk, 0, stream>>>(hbuf, xb, colsum, g1, be1, N);  // -> h1 bf16

  // ---------------- layer 2 (BN folded into seg_norm_all) ----------------
  hipMemsetAsync(agg, 0, aggSpan, stream);
  edge_gemm_mfma<<<gridEdge, blk, 0, stream>>>(xb, W2tb, ssrc, sdst, chunk_rel, agg);
  gemm_mfma<true, 2, false><<<gridDual, blk, 0, stream>>>(
      xb, lwT2b, rW2b, b2, resb2, agg, hbuf, nullptr, colsum, N, HD, HD);  // hbuf = pre-BN h2

  // ---------------- readout ----------------
  hipMemsetAsync(gsum, 0, (readout_end - (size_t)(gsum - ws)) * sizeof(float), stream);
  seg_accum2<<<(N + NPB - 1) / NPB, blk, 0, stream>>>(hbuf, gids, mids, gsum, gcnt, msum, mcnt, N);
  float invM = 1.f / (float)N;
  seg_norm_all<<<((NG + NM) * HD + 255) / 256, blk, 0, stream>>>(
      gsum, gcnt, msum, mcnt, colsum, g2, be2, invM, out_gf, headin, NG, NM);

  // ---- unified head over 7500 rows: 3 GEMMs, last writes straight to d_out ----
  dim3 gA(FFN / 64, (NHEAD + 63) / 64);
  gemm_mfma<false, 0, true><<<gA, blk, 0, stream>>>(
      headin, featWb, nullptr, featb, nullptr, nullptr, nullptr, fbuf_b, nullptr, NHEAD, FFN, HD);
  gemm_mfma<false, 1, true><<<gA, blk, 0, stream>>>(
      fbuf_b, mW1b, nullptr, mb1, nullptr, nullptr, nullptr, obuf_b, nullptr, NHEAD, FFN, FFN);
  dim3 gC(OUT2 / 64, (NHEAD + 63) / 64);
  gemm_mfma<false, 0, false><<<gC, blk, 0, stream>>>(
      obuf_b, mW2b, nullptr, mb2, nullptr, nullptr, out_gl, nullptr, nullptr, NHEAD, OUT2, FFN);
}